// Round 12
// baseline (462.182 us; speedup 1.0000x reference)
//
#include <hip/hip_runtime.h>
#include <math.h>

// N=50000, F=256, H=256, C=40, E=800000; CURV=1, EPS=4e-3 -> maxnorm=0.996

typedef short bf16x8 __attribute__((ext_vector_type(8)));
typedef float f32x4 __attribute__((ext_vector_type(4)));

#define AS1 __attribute__((address_space(1)))
#define AS3 __attribute__((address_space(3)))

// pack two fp32 -> bf16x2 (round-half-up) : low short = a, high short = b
__device__ inline unsigned pack_bf16_hu(float a, float b) {
    unsigned ua = __float_as_uint(a) + 0x8000u;
    unsigned ub = __float_as_uint(b) + 0x8000u;
    return __builtin_amdgcn_perm(ub, ua, 0x07060302u);
}

__device__ inline unsigned short f2bf_rne(float x) {
    unsigned u = __float_as_uint(x);
    unsigned r = (u + 0x7fffu + ((u >> 16) & 1u)) >> 16;
    return (unsigned short)r;
}

// split (a,b) into hi bf16 pair + residual-lo bf16 pair (packed uints)
__device__ inline void split2(float a, float b, unsigned* hw, unsigned* lw) {
    unsigned ua = __float_as_uint(a) + 0x8000u;
    unsigned ub = __float_as_uint(b) + 0x8000u;
    *hw = __builtin_amdgcn_perm(ub, ua, 0x07060302u);
    float ra = a - __uint_as_float(ua & 0xFFFF0000u);
    float rb = b - __uint_as_float(ub & 0xFFFF0000u);
    unsigned va = __float_as_uint(ra) + 0x8000u;
    unsigned vb = __float_as_uint(rb) + 0x8000u;
    *lw = __builtin_amdgcn_perm(vb, va, 0x07060302u);
}

// ---------------- CSR build ----------------

__global__ void k_count(const int* __restrict__ dst, int* __restrict__ deg, int E) {
    int e = blockIdx.x * 256 + threadIdx.x;
    if (e < E) atomicAdd(&deg[dst[e]], 1);
}

__global__ __launch_bounds__(256) void k_scanA(const int* __restrict__ deg,
                                               int* __restrict__ offs,
                                               float* __restrict__ invc,
                                               int* __restrict__ bsum, int N) {
    __shared__ int wt[4];
    int tid = threadIdx.x, lane = tid & 63, wid = tid >> 6;
    int base = blockIdx.x * 1024 + tid * 4;
    int v[4];
    #pragma unroll
    for (int j = 0; j < 4; ++j) {
        int i = base + j;
        v[j] = (i < N) ? deg[i] : 0;
        if (i < N) invc[i] = 1.0f / (float)max(v[j], 1);
    }
    int t = v[0] + v[1] + v[2] + v[3];
    int s = t;
    #pragma unroll
    for (int d = 1; d < 64; d <<= 1) {
        int u = __shfl_up(s, d);
        if (lane >= d) s += u;
    }
    if (lane == 63) wt[wid] = s;
    __syncthreads();
    int wpre = 0, btot = 0;
    #pragma unroll
    for (int q = 0; q < 4; ++q) {
        int x = wt[q];
        btot += x;
        if (q < wid) wpre += x;
    }
    int run = wpre + s - t;
    #pragma unroll
    for (int j = 0; j < 4; ++j) {
        int i = base + j;
        if (i < N) offs[i] = run;
        run += v[j];
    }
    if (tid == 0) bsum[blockIdx.x] = btot;
}

__global__ __launch_bounds__(64) void k_scanB(int* __restrict__ bsum,
                                              int* __restrict__ offs, int N, int G) {
    int lane = threadIdx.x;
    int run = 0;
    for (int base = 0; base < G; base += 64) {
        int i = base + lane;
        int v = (i < G) ? bsum[i] : 0;
        int s = v;
        #pragma unroll
        for (int d = 1; d < 64; d <<= 1) {
            int u = __shfl_up(s, d);
            if (lane >= d) s += u;
        }
        int tot = __shfl(s, 63);
        if (i < G) bsum[i] = run + s - v;
        run += tot;
    }
    if (lane == 0) offs[N] = run;
}

__global__ __launch_bounds__(256) void k_scanC(int* __restrict__ offs,
                                               const int* __restrict__ bsum, int N) {
    int add = bsum[blockIdx.x];
    int base = blockIdx.x * 1024 + threadIdx.x * 4;
    #pragma unroll
    for (int j = 0; j < 4; ++j) {
        int i = base + j;
        if (i < N) offs[i] += add;
    }
}

__global__ void k_scatter(const int* __restrict__ src, const int* __restrict__ dst,
                          const int* __restrict__ offs, int* __restrict__ cursor,
                          int* __restrict__ ssrc, int E) {
    int e = blockIdx.x * 256 + threadIdx.x;
    if (e >= E) return;
    int d = dst[e];
    int pos = offs[d] + atomicAdd(&cursor[d], 1);
    ssrc[pos] = src[e];
}

// ---------------- weight prep ----------------
// k_wsplit0 v2: emits FRAGMENT-ORDERED Bf for gemm0.
// Bf[(w*8+g)*4+nf][lane][8] bf16: per-slot 64 lanes x 16B contiguous (1 KB wave load).

__global__ __launch_bounds__(256) void k_wsplit0(const float* __restrict__ Wl,
                                                 const float* __restrict__ Wr,
                                                 unsigned short* __restrict__ Bfh,
                                                 unsigned short* __restrict__ Bfl) {
    int idx = blockIdx.x * 256 + threadIdx.x;   // < 8*8*4*64 = 16384 lane-chunks
    int lane = idx & 63;
    int nf = (idx >> 6) & 3;
    int g  = (idx >> 8) & 7;
    int w  = (idx >> 11) & 7;
    int ml = lane & 15, quad = lane >> 4;
    int wc = w & 3;
    int n = (w < 4) ? (wc * 64 + (nf & 2) * 16 + 2 * ml + (nf & 1))
                    : (256 + wc * 64 + nf * 16 + ml);
    int kbase = g * 32 + quad * 8;
    unsigned short h8[8], l8[8];
    #pragma unroll
    for (int e = 0; e < 8; ++e) {
        int k = kbase + e;
        float v = (n < 256) ? Wl[k * 256 + n] : Wr[k * 256 + (n - 256)];
        unsigned short h = f2bf_rne(v);
        float hf = __uint_as_float(((unsigned)h) << 16);
        h8[e] = h;
        l8[e] = f2bf_rne(v - hf);
    }
    *(uint4*)&Bfh[(size_t)idx * 8] = *(uint4*)h8;
    *(uint4*)&Bfl[(size_t)idx * 8] = *(uint4*)l8;
}

__global__ __launch_bounds__(256) void k_wsplit1(const float* __restrict__ Wl,
                                                 const float* __restrict__ Wr,
                                                 unsigned short* __restrict__ Wth,
                                                 unsigned short* __restrict__ Wtl) {
    int idx = blockIdx.x * 256 + threadIdx.x;   // < 80*256
    if (idx >= 80 * 256) return;
    int n = idx >> 8, k = idx & 255;
    float v = (n < 40) ? Wl[k * 40 + n] : Wr[k * 40 + (n - 40)];
    unsigned short h = f2bf_rne(v);
    float hf = __uint_as_float(((unsigned)h) << 16);
    Wth[idx] = h;
    Wtl[idx] = f2bf_rne(v - hf);
}

// ---------------- X pre-split: X fp32 -> Xh/Xl bf16, chunk-XOR-swizzled rows ----------------

__global__ __launch_bounds__(256) void k_xsplit(const float* __restrict__ X,
                                                unsigned short* __restrict__ Xh,
                                                unsigned short* __restrict__ Xl,
                                                int N) {
    int idx = blockIdx.x * 256 + threadIdx.x;   // n*32 + c over Npad rows
    int n = idx >> 5, c = idx & 31;
    float4 v0 = make_float4(0.f, 0.f, 0.f, 0.f);
    float4 v1 = make_float4(0.f, 0.f, 0.f, 0.f);
    if (n < N) {
        v0 = *(const float4*)&X[(size_t)n * 256 + c * 8];
        v1 = *(const float4*)&X[(size_t)n * 256 + c * 8 + 4];
    }
    unsigned h0, l0, h1, l1, h2, l2, h3, l3;
    split2(v0.x, v0.y, &h0, &l0);
    split2(v0.z, v0.w, &h1, &l1);
    split2(v1.x, v1.y, &h2, &l2);
    split2(v1.z, v1.w, &h3, &l3);
    int cp = c ^ (n & 7);
    size_t o = (size_t)n * 256 + cp * 8;
    *(uint4*)&Xh[o] = make_uint4(h0, h1, h2, h3);
    *(uint4*)&Xl[o] = make_uint4(l0, l1, l2, l3);
}

// ---------------- gemm0 v7: v6 + __launch_bounds__(512,4) -> 2 blocks/CU ----------------
// v6 post-mortem: 2-phase stage gave only ~3us -> residual stall is B-load latency with
// 1 lockstep block/CU. v7: cap unified regs at 128 (4 waves/SIMD) so TWO M=64 blocks
// co-reside (LDS 2x64KB=128<=160KB); cross-block overlap hides B latency + stage drain.
// Constant per-wave intensity (round-6 lesson: never trade intensity for occupancy).

__global__ __launch_bounds__(512, 4) void gemm0_mfma(const unsigned short* __restrict__ Xh,
                                                     const unsigned short* __restrict__ Xl,
                                                     const unsigned short* __restrict__ Bfh,
                                                     const unsigned short* __restrict__ Bfl,
                                                     unsigned short* __restrict__ Yl,
                                                     float* __restrict__ Yr, int N) {
    __shared__ __align__(16) unsigned short AhL[2][64 * 128];
    __shared__ __align__(16) unsigned short AlL[2][64 * 128];

    int tid = threadIdx.x;
    int lane = tid & 63;
    int w = __builtin_amdgcn_readfirstlane(tid >> 6);   // 0..7
    int ml = lane & 15, quad = lane >> 4;
    int m0 = blockIdx.x * 64;
    bool isYl = (w < 4);
    int wc = w & 3;

    // stage K-half h (256B/row) of rows m0..m0+63 -> linear LDS buffer h
    auto stage = [&](int h) {
        #pragma unroll
        for (int j = 0; j < 2; ++j) {
            int idx = j * 512 + tid;            // 0..1023 16B-chunks
            int row = idx >> 4, c16 = idx & 15;
            size_t gsrc = (size_t)(m0 + row) * 512 + (size_t)h * 256 + c16 * 16;
            int loff = idx * 16;
            __builtin_amdgcn_global_load_lds((const AS1 unsigned*)((const char*)Xh + gsrc),
                                             (AS3 unsigned*)((char*)&AhL[h][0] + loff), 16, 0, 0);
            __builtin_amdgcn_global_load_lds((const AS1 unsigned*)((const char*)Xl + gsrc),
                                             (AS3 unsigned*)((char*)&AlL[h][0] + loff), 16, 0, 0);
        }
    };

    stage(0);

    f32x4 acc[4][4];
    #pragma unroll
    for (int a = 0; a < 4; ++a)
        #pragma unroll
        for (int b = 0; b < 4; ++b) acc[a][b] = (f32x4){0.f, 0.f, 0.f, 0.f};

    bf16x8 bh0[4], bl0[4], bh1[4], bl1[4];

    // fragment-ordered B: slot (w*8+g)*4+nf, per-lane 16B contiguous
    auto loadB = [&](int it, bf16x8* bh, bf16x8* bl) {
        size_t base = (((size_t)(w * 8 + it) * 4) * 64 + lane) * 8;
        #pragma unroll
        for (int nf = 0; nf < 4; ++nf) {
            bh[nf] = *(const bf16x8*)&Bfh[base + (size_t)nf * 512];
            bl[nf] = *(const bf16x8*)&Bfl[base + (size_t)nf * 512];
        }
    };

    loadB(0, bh0, bl0);
    __syncthreads();   // drains stage(0): half-0 ready (32KB, not 64KB)

    int swz = ml & 7;

    #pragma unroll
    for (int p = 0; p < 2; ++p) {
        if (p == 0) stage(1);               // half-1 in flight across half-0 compute
        const char* base_h = (const char*)&AhL[p][0];
        const char* base_l = (const char*)&AlL[p][0];
        #pragma unroll
        for (int g2 = 0; g2 < 4; ++g2) {
            int g = p * 4 + g2;
            bf16x8* bhc = (g & 1) ? bh1 : bh0;
            bf16x8* blc = (g & 1) ? bl1 : bl0;
            bf16x8* bhn = (g & 1) ? bh0 : bh1;
            bf16x8* bln = (g & 1) ? bl0 : bl1;
            if (g < 7) loadB(g + 1, bhn, bln);
            bf16x8 ah[4], al[4];
            #pragma unroll
            for (int mf = 0; mf < 4; ++mf) {
                int ro = (mf * 16 + ml) * 256 + (((g2 * 4 + quad) ^ swz) * 16);
                ah[mf] = *(const bf16x8*)(base_h + ro);
                al[mf] = *(const bf16x8*)(base_l + ro);
            }
            #pragma unroll
            for (int nf = 0; nf < 4; ++nf)
                #pragma unroll
                for (int mf = 0; mf < 4; ++mf) {
                    acc[mf][nf] = __builtin_amdgcn_mfma_f32_16x16x32_bf16(ah[mf], bhc[nf], acc[mf][nf], 0, 0, 0);
                    acc[mf][nf] = __builtin_amdgcn_mfma_f32_16x16x32_bf16(ah[mf], blc[nf], acc[mf][nf], 0, 0, 0);
                    acc[mf][nf] = __builtin_amdgcn_mfma_f32_16x16x32_bf16(al[mf], bhc[nf], acc[mf][nf], 0, 0, 0);
                }
        }
        if (p == 0) __syncthreads();        // drains stage(1); all half-0 reads done
    }

    if (isYl) {
        #pragma unroll
        for (int mf = 0; mf < 4; ++mf)
            #pragma unroll
            for (int r = 0; r < 4; ++r) {
                int row = m0 + mf * 16 + quad * 4 + r;
                if (row < N) {
                    unsigned p0 = pack_bf16_hu(acc[mf][0][r], acc[mf][1][r]);
                    unsigned p1 = pack_bf16_hu(acc[mf][2][r], acc[mf][3][r]);
                    *(unsigned*)&Yl[(size_t)row * 256 + wc * 64 + 2 * ml] = p0;
                    *(unsigned*)&Yl[(size_t)row * 256 + wc * 64 + 32 + 2 * ml] = p1;
                }
            }
    } else {
        #pragma unroll
        for (int mf = 0; mf < 4; ++mf)
            #pragma unroll
            for (int r = 0; r < 4; ++r) {
                int row = m0 + mf * 16 + quad * 4 + r;
                if (row < N) {
                    #pragma unroll
                    for (int nf = 0; nf < 4; ++nf)
                        Yr[(size_t)row * 256 + wc * 64 + nf * 16 + ml] = acc[mf][nf][r];
                }
            }
    }
}

// ---------------- combine0 v3: 1 node/wave + 8-deep MLP + dense node-major H writes ----------------

__global__ __launch_bounds__(256) void combine0(const unsigned short* __restrict__ Yl,
                                                const float* __restrict__ Yr,
                                                const int* __restrict__ offs,
                                                const int* __restrict__ ssrc,
                                                const float* __restrict__ invc,
                                                const float* __restrict__ bl0,
                                                unsigned short* __restrict__ Hh,
                                                unsigned short* __restrict__ Hl, int N) {
    int wv = threadIdx.x >> 6, lane = threadIdx.x & 63;
    int n = blockIdx.x * 4 + wv;
    if (n >= N) return;
    int e0 = offs[n], e1 = offs[n + 1];
    float4 acc = make_float4(0.f, 0.f, 0.f, 0.f);
    int e = e0;
    for (; e + 7 < e1; e += 8) {
        int s0 = ssrc[e],     s1 = ssrc[e + 1], s2 = ssrc[e + 2], s3 = ssrc[e + 3];
        int s4 = ssrc[e + 4], s5 = ssrc[e + 5], s6 = ssrc[e + 6], s7 = ssrc[e + 7];
        uint2 p0 = *(const uint2*)&Yl[(size_t)s0 * 256 + lane * 4];
        uint2 p1 = *(const uint2*)&Yl[(size_t)s1 * 256 + lane * 4];
        uint2 p2 = *(const uint2*)&Yl[(size_t)s2 * 256 + lane * 4];
        uint2 p3 = *(const uint2*)&Yl[(size_t)s3 * 256 + lane * 4];
        uint2 p4 = *(const uint2*)&Yl[(size_t)s4 * 256 + lane * 4];
        uint2 p5 = *(const uint2*)&Yl[(size_t)s5 * 256 + lane * 4];
        uint2 p6 = *(const uint2*)&Yl[(size_t)s6 * 256 + lane * 4];
        uint2 p7 = *(const uint2*)&Yl[(size_t)s7 * 256 + lane * 4];
        acc.x += ((__uint_as_float(p0.x << 16) + __uint_as_float(p1.x << 16)) +
                  (__uint_as_float(p2.x << 16) + __uint_as_float(p3.x << 16))) +
                 ((__uint_as_float(p4.x << 16) + __uint_as_float(p5.x << 16)) +
                  (__uint_as_float(p6.x << 16) + __uint_as_float(p7.x << 16)));
        acc.y += ((__uint_as_float(p0.x & 0xFFFF0000u) + __uint_as_float(p1.x & 0xFFFF0000u)) +
                  (__uint_as_float(p2.x & 0xFFFF0000u) + __uint_as_float(p3.x & 0xFFFF0000u))) +
                 ((__uint_as_float(p4.x & 0xFFFF0000u) + __uint_as_float(p5.x & 0xFFFF0000u)) +
                  (__uint_as_float(p6.x & 0xFFFF0000u) + __uint_as_float(p7.x & 0xFFFF0000u)));
        acc.z += ((__uint_as_float(p0.y << 16) + __uint_as_float(p1.y << 16)) +
                  (__uint_as_float(p2.y << 16) + __uint_as_float(p3.y << 16))) +
                 ((__uint_as_float(p4.y << 16) + __uint_as_float(p5.y << 16)) +
                  (__uint_as_float(p6.y << 16) + __uint_as_float(p7.y << 16)));
        acc.w += ((__uint_as_float(p0.y & 0xFFFF0000u) + __uint_as_float(p1.y & 0xFFFF0000u)) +
                  (__uint_as_float(p2.y & 0xFFFF0000u) + __uint_as_float(p3.y & 0xFFFF0000u))) +
                 ((__uint_as_float(p4.y & 0xFFFF0000u) + __uint_as_float(p5.y & 0xFFFF0000u)) +
                  (__uint_as_float(p6.y & 0xFFFF0000u) + __uint_as_float(p7.y & 0xFFFF0000u)));
    }
    for (; e + 3 < e1; e += 4) {
        int s0 = ssrc[e], s1 = ssrc[e + 1], s2 = ssrc[e + 2], s3 = ssrc[e + 3];
        uint2 p = *(const uint2*)&Yl[(size_t)s0 * 256 + lane * 4];
        uint2 q = *(const uint2*)&Yl[(size_t)s1 * 256 + lane * 4];
        uint2 v = *(const uint2*)&Yl[(size_t)s2 * 256 + lane * 4];
        uint2 t = *(const uint2*)&Yl[(size_t)s3 * 256 + lane * 4];
        acc.x += (__uint_as_float(p.x << 16) + __uint_as_float(q.x << 16)) +
                 (__uint_as_float(v.x << 16) + __uint_as_float(t.x << 16));
        acc.y += (__uint_as_float(p.x & 0xFFFF0000u) + __uint_as_float(q.x & 0xFFFF0000u)) +
                 (__uint_as_float(v.x & 0xFFFF0000u) + __uint_as_float(t.x & 0xFFFF0000u));
        acc.z += (__uint_as_float(p.y << 16) + __uint_as_float(q.y << 16)) +
                 (__uint_as_float(v.y << 16) + __uint_as_float(t.y << 16));
        acc.w += (__uint_as_float(p.y & 0xFFFF0000u) + __uint_as_float(q.y & 0xFFFF0000u)) +
                 (__uint_as_float(v.y & 0xFFFF0000u) + __uint_as_float(t.y & 0xFFFF0000u));
    }
    for (; e < e1; ++e) {
        int s0 = ssrc[e];
        uint2 p = *(const uint2*)&Yl[(size_t)s0 * 256 + lane * 4];
        acc.x += __uint_as_float(p.x << 16);
        acc.y += __uint_as_float(p.x & 0xFFFF0000u);
        acc.z += __uint_as_float(p.y << 16);
        acc.w += __uint_as_float(p.y & 0xFFFF0000u);
    }
    float ic = invc[n];
    float4 b = *(const float4*)&bl0[lane * 4];
    float4 yr = *(const float4*)&Yr[(size_t)n * 256 + lane * 4];
    float hx = fmaxf(acc.x * ic + b.x + yr.x, 0.f);
    float hy = fmaxf(acc.y * ic + b.y + yr.y, 0.f);
    float hz = fmaxf(acc.z * ic + b.z + yr.z, 0.f);
    float hw = fmaxf(acc.w * ic + b.w + yr.w, 0.f);
    unsigned h0, h1, l0, l1;
    split2(hx, hy, &h0, &l0);
    split2(hz, hw, &h1, &l1);
    size_t offH = (size_t)n * 256 + lane * 4;   // node-major, fragment-k order: dense 512B/node
    *(uint2*)&Hh[offH] = make_uint2(h0, h1);
    *(uint2*)&Hl[offH] = make_uint2(l0, l1);
}

// ---------------- gemm1 v2: reads node-major fragment-k H layout ----------------

__global__ __launch_bounds__(256) void gemm1_mfma(const unsigned short* __restrict__ Hh,
                                                  const unsigned short* __restrict__ Hl,
                                                  const unsigned short* __restrict__ Bh,
                                                  const unsigned short* __restrict__ Bl,
                                                  unsigned short* __restrict__ Zl,
                                                  float* __restrict__ Zr, int N, int numTiles) {
    int tid = threadIdx.x;
    int lane = tid & 63;
    int w = __builtin_amdgcn_readfirstlane(tid >> 6);
    int ml = lane & 15, quad = lane >> 4;
    int t = blockIdx.x * 4 + w;
    if (t >= numTiles) return;

    const unsigned short* ahp = Hh + (size_t)(t * 16 + ml) * 256 + quad * 8;
    const unsigned short* alp = Hl + (size_t)(t * 16 + ml) * 256 + quad * 8;

    f32x4 acc[5];
    #pragma unroll
    for (int b = 0; b < 5; ++b) acc[b] = (f32x4){0.f, 0.f, 0.f, 0.f};

    #pragma unroll
    for (int kc = 0; kc < 8; ++kc) {
        bf16x8 ah = *(const bf16x8*)&ahp[kc * 32];
        bf16x8 al = *(const bf16x8*)&alp[kc * 32];
        int ko = kc * 32 + quad * 8;
        #pragma unroll
        for (int nf = 0; nf < 5; ++nf) {
            size_t bo = (size_t)(nf * 16 + ml) * 256 + ko;
            bf16x8 bh = *(const bf16x8*)&Bh[bo];
            bf16x8 bl = *(const bf16x8*)&Bl[bo];
            acc[nf] = __builtin_amdgcn_mfma_f32_16x16x32_bf16(ah, bh, acc[nf], 0, 0, 0);
            acc[nf] = __builtin_amdgcn_mfma_f32_16x16x32_bf16(ah, bl, acc[nf], 0, 0, 0);
            acc[nf] = __builtin_amdgcn_mfma_f32_16x16x32_bf16(al, bh, acc[nf], 0, 0, 0);
        }
    }
    #pragma unroll
    for (int r = 0; r < 4; ++r) {
        int n = t * 16 + quad * 4 + r;
        if (n < N) {
            #pragma unroll
            for (int nf = 0; nf < 5; ++nf) {
                int col = nf * 16 + ml;
                if (col < 40) Zl[(size_t)n * 40 + col] = f2bf_rne(acc[nf][r]);
                else Zr[(size_t)n * 40 + (col - 40)] = acc[nf][r];
            }
        }
    }
}

// ---------------- combine1: bf16 Zl gather ----------------

__global__ __launch_bounds__(256) void combine1(const unsigned short* __restrict__ Zl,
                                                const float* __restrict__ Zr,
                                                const int* __restrict__ offs,
                                                const int* __restrict__ ssrc,
                                                const float* __restrict__ invc,
                                                const float* __restrict__ bl1,
                                                float* __restrict__ H2, int N) {
    int wv = threadIdx.x >> 6, lane = threadIdx.x & 63;
    int n = blockIdx.x * 4 + wv;
    if (n >= N) return;
    if (lane >= 40) return;
    int e0 = offs[n], e1 = offs[n + 1];
    float acc = 0.f;
    int e = e0;
    for (; e + 1 < e1; e += 2) {
        int s0 = ssrc[e], s1 = ssrc[e + 1];
        unsigned a = Zl[(size_t)s0 * 40 + lane];
        unsigned b = Zl[(size_t)s1 * 40 + lane];
        acc += __uint_as_float(a << 16) + __uint_as_float(b << 16);
    }
    if (e < e1) {
        unsigned a = Zl[(size_t)ssrc[e] * 40 + lane];
        acc += __uint_as_float(a << 16);
    }
    float v = acc * invc[n] + bl1[lane] + Zr[(size_t)n * 40 + lane];
    H2[(size_t)n * 40 + lane] = v;
}

// ---------------- W_lin pre-convert v2: fragment-ordered WbF ----------------
// WbF[slot][lane][8] bf16, slot = (c*3+s)*3+cf (c=0..19, s=0..2, cf=0..2), lane=0..63.

__global__ __launch_bounds__(256) void k_wprep(const float* __restrict__ W,
                                               unsigned short* __restrict__ WbF) {
    int idx = blockIdx.x * 256 + threadIdx.x;   // chunk index < 180*64
    if (idx >= 180 * 64) return;
    int slot = idx >> 6, lane = idx & 63;
    int cf = slot % 3;
    int cs = slot / 3;
    int s = cs % 3;
    int c = cs / 3;
    int ml = lane & 15, quad = lane >> 4;
    int col = cf * 16 + ml;
    int kbase = c * 96 + s * 32 + quad * 8;
    unsigned short v8[8];
    #pragma unroll
    for (int e = 0; e < 8; ++e) {
        int kp = kbase + e;
        int i = kp / 48;
        int j = kp - i * 48;
        float v = 0.f;
        if (col < 40 && i < 40 && j < 40) v = W[((size_t)(i * 40 + j)) * 40 + col];
        v8[e] = f2bf_rne(v);
    }
    *(uint4*)&WbF[(size_t)idx * 8] = *(uint4*)v8;
}

// ---------------- k_final_mfma v4: register windows + coalesced WbF + free VGPR budget ----

__global__ __launch_bounds__(256, 1) void k_final_mfma(const float* __restrict__ H2,
                                                       const unsigned short* __restrict__ WbF,
                                                       const float* __restrict__ blin,
                                                       float* __restrict__ out, int N) {
    int tid = threadIdx.x;
    int m0 = blockIdx.x * 64;
    int lane = tid & 63;
    int w = __builtin_amdgcn_readfirstlane(tid >> 6);
    int ml = lane & 15;
    int quad = lane >> 4;
    int row = w * 16 + ml;
    int gn = m0 + row;

    float g[48];
    float s2 = 0.f;
    #pragma unroll
    for (int q4 = 0; q4 < 10; ++q4) {
        float4 v = make_float4(0.f, 0.f, 0.f, 0.f);
        if (gn < N) v = *(const float4*)&H2[(size_t)gn * 40 + q4 * 4];
        g[q4 * 4 + 0] = v.x; g[q4 * 4 + 1] = v.y;
        g[q4 * 4 + 2] = v.z; g[q4 * 4 + 3] = v.w;
        s2 += v.x * v.x + v.y * v.y + v.z * v.z + v.w * v.w;
    }
    #pragma unroll
    for (int j = 40; j < 48; ++j) g[j] = 0.f;

    float aln = atanhf(fminf(fmaxf(s2, 1e-15f), 0.996f)) / fmaxf(s2, 1e-30f);

    bool isQ0 = (quad == 0), isQ2 = (quad == 2), qLo = (quad < 2);
    float wA[8], wB[8], wC[8];
    #pragma unroll
    for (int j = 0; j < 8; ++j) {
        float a0 = isQ0 ? g[j] : g[8 + j];
        float a1 = isQ2 ? g[16 + j] : g[24 + j];
        wA[j] = qLo ? a0 : a1;
        float b0 = isQ0 ? g[32 + j] : g[40 + j];
        float b1 = isQ2 ? g[j] : g[8 + j];
        wB[j] = qLo ? b0 : b1;
        float c0 = isQ0 ? g[16 + j] : g[24 + j];
        float c1 = isQ2 ? g[32 + j] : g[40 + j];
        wC[j] = qLo ? c0 : c1;
    }

    f32x4 acc[3];
    #pragma unroll
    for (int c = 0; c < 3; ++c) acc[c] = (f32x4){0.f, 0.f, 0.f, 0.f};

    const unsigned short* bw = WbF + (size_t)lane * 8;

    #pragma unroll
    for (int c = 0; c < 20; ++c) {
        float gi0 = g[2 * c];
        float gi1 = qLo ? g[2 * c] : g[2 * c + 1];
        float gi2 = g[2 * c + 1];
        {
            const int slot = (c * 3 + 0) * 3;
            union { unsigned u[4]; bf16x8 v; } A;
            A.u[0] = pack_bf16_hu(gi0 * wA[0], gi0 * wA[1]);
            A.u[1] = pack_bf16_hu(gi0 * wA[2], gi0 * wA[3]);
            A.u[2] = pack_bf16_hu(gi0 * wA[4], gi0 * wA[5]);
            A.u[3] = pack_bf16_hu(gi0 * wA[6], gi0 * wA[7]);
            #pragma unroll
            for (int cf = 0; cf < 3; ++cf) {
                bf16x8 bf = *(const bf16x8*)&bw[(size_t)(slot + cf) * 512];
                acc[cf] = __builtin_amdgcn_mfma_f32_16x16x32_bf16(A.v, bf, acc[cf], 0, 0, 0);
            }
        }
        {
            const int slot = (c * 3 + 1) * 3;
            union { unsigned u[4]; bf16x8 v; } A;
            A.u[0] = pack_bf16_hu(gi1 * wB[0], gi1 * wB[1]);
            A.u[1] = pack_bf16_hu(gi1 * wB[2], gi1 * wB[3]);
            A.u[2] = pack_bf16_hu(gi1 * wB[4], gi1 * wB[5]);
            A.u[3] = pack_bf16_hu(gi1 * wB[6], gi1 * wB[7]);
            #pragma unroll
            for (int cf = 0; cf < 3; ++cf) {
                bf16x8 bf = *(const bf16x8*)&bw[(size_t)(slot + cf) * 512];
                acc[cf] = __builtin_amdgcn_mfma_f32_16x16x32_bf16(A.v, bf, acc[cf], 0, 0, 0);
            }
        }
        {
            const int slot = (c * 3 + 2) * 3;
            union { unsigned u[4]; bf16x8 v; } A;
            A.u[0] = pack_bf16_hu(gi2 * wC[0], gi2 * wC[1]);
            A.u[1] = pack_bf16_hu(gi2 * wC[2], gi2 * wC[3]);
            A.u[2] = pack_bf16_hu(gi2 * wC[4], gi2 * wC[5]);
            A.u[3] = pack_bf16_hu(gi2 * wC[6], gi2 * wC[7]);
            #pragma unroll
            for (int cf = 0; cf < 3; ++cf) {
                bf16x8 bf = *(const bf16x8*)&bw[(size_t)(slot + cf) * 512];
                acc[cf] = __builtin_amdgcn_mfma_f32_16x16x32_bf16(A.v, bf, acc[cf], 0, 0, 0);
            }
        }
    }

    float bcol[3];
    #pragma unroll
    for (int c = 0; c < 3; ++c) {
        int col = c * 16 + ml;
        bcol[c] = (col < 40) ? blin[col] : 0.f;
    }
    bool v2 = (ml < 8);

    #pragma unroll
    for (int r = 0; r < 4; ++r) {
        int nloc = w * 16 + quad * 4 + r;
        float al = __shfl(aln, quad * 4 + r);
        float u0 = al * acc[0][r] + bcol[0];
        float u1 = al * acc[1][r] + bcol[1];
        float u2 = v2 ? (al * acc[2][r] + bcol[2]) : 0.f;
        float un2 = u0 * u0 + u1 * u1 + u2 * u2;
        #pragma unroll
        for (int m = 1; m < 16; m <<= 1) un2 += __shfl_xor(un2, m);
        float un = fmaxf(sqrtf(un2), 1e-15f);
        float tnh = tanhf(un);
        float gma = tnh / un;
        float ps = (tnh > 0.996f) ? (0.996f / tnh) : 1.0f;
        float s = gma * ps;
        float l0 = s * u0, l1 = s * u1, l2 = s * u2;
        float mx = fmaxf(l0, l1);
        if (v2) mx = fmaxf(mx, l2);
        #pragma unroll
        for (int m = 1; m < 16; m <<= 1) mx = fmaxf(mx, __shfl_xor(mx, m));
        float se = expf(l0 - mx) + expf(l1 - mx) + (v2 ? expf(l2 - mx) : 0.f);
        #pragma unroll
        for (int m = 1; m < 16; m <<= 1) se += __shfl_xor(se, m);
        float lse = logf(se);
        int go = m0 + nloc;
        if (go < N) {
            out[(size_t)go * 40 + ml] = l0 - mx - lse;
            out[(size_t)go * 40 + 16 + ml] = l1 - mx - lse;
            if (v2) out[(size_t)go * 40 + 32 + ml] = l2 - mx - lse;
        }
    }
}

// ---------------- launch ----------------

extern "C" void kernel_launch(void* const* d_in, const int* in_sizes, int n_in,
                              void* d_out, int out_size, void* d_ws, size_t ws_size,
                              hipStream_t stream) {
    const float* x    = (const float*)d_in[0];
    const int*   ei   = (const int*)d_in[1];
    const float* Wl0  = (const float*)d_in[2];
    const float* bl0  = (const float*)d_in[3];
    const float* Wr0  = (const float*)d_in[4];
    const float* Wl1  = (const float*)d_in[5];
    const float* bl1  = (const float*)d_in[6];
    const float* Wr1  = (const float*)d_in[7];
    const float* Wlin = (const float*)d_in[8];
    const float* blin = (const float*)d_in[9];
    int N = in_sizes[0] / 256;
    int E = in_sizes[1] / 2;
    const int* src = ei;
    const int* dst = ei + E;
    int numTiles = (N + 15) / 16;
    int Npad = ((N + 63) / 64) * 64;          // gemm0 tile-padded row count

    char* ws = (char*)d_ws;
    size_t off = 0;
    auto carve = [&](size_t bytes) -> char* {
        char* p = ws + off;
        off = (off + bytes + 255) & ~(size_t)255;
        return p;
    };
    size_t xbytes = (size_t)Npad * 256 * 2;   // >= numTiles*4096*2
    int*   deg    = (int*)carve((size_t)N * 4);
    int*   cursor = (int*)carve((size_t)N * 4);
    int*   offs   = (int*)carve((size_t)(N + 1) * 4);
    float* invc   = (float*)carve((size_t)N * 4);
    int*   bsum   = (int*)carve(1024);
    int*   ssrc   = (int*)carve((size_t)E * 4);
    unsigned short* Yl = (unsigned short*)carve((size_t)N * 256 * 2);
    float* Yr     = (float*)carve((size_t)N * 256 * 4);
    unsigned short* Hh = (unsigned short*)carve(xbytes);
    unsigned short* Hl = (unsigned short*)carve(xbytes);
    unsigned short* Zl = (unsigned short*)carve((size_t)N * 40 * 2);
    float* Zr     = (float*)carve((size_t)N * 40 * 4);
    float* H2     = (float*)carve((size_t)N * 40 * 4);
    // Xh/Xl (pre-split, swizzled X) alias Hh/Hl: dead before combine0 writes Hh/Hl
    unsigned short* Xh = Hh;
    unsigned short* Xl = Hl;
    // WbF (180*64*8 bf16 = 184 KB) aliases Yr (dead after combine0)
    unsigned short* Wb = (unsigned short*)Yr;
    // split weights alias H2 (written only at combine1, after gemm1)
    unsigned short* Wth  = (unsigned short*)H2;    // gemm0 fragment B: 256 KB
    unsigned short* Wtl  = Wth + 512 * 256;        // 256 KB
    unsigned short* Wt1h = Wtl + 512 * 256;
    unsigned short* Wt1l = Wt1h + 80 * 256;

    int G = (N + 1023) / 1024;

    hipMemsetAsync(deg, 0, (size_t)N * 4, stream);
    hipMemsetAsync(cursor, 0, (size_t)N * 4, stream);

    k_count<<<(E + 255) / 256, 256, 0, stream>>>(dst, deg, E);
    k_scanA<<<G, 256, 0, stream>>>(deg, offs, invc, bsum, N);
    k_scanB<<<1, 64, 0, stream>>>(bsum, offs, N, G);
    k_scanC<<<G, 256, 0, stream>>>(offs, bsum, N);
    k_scatter<<<(E + 255) / 256, 256, 0, stream>>>(src, dst, offs, cursor, ssrc, E);
    k_wsplit0<<<64, 256, 0, stream>>>(Wl0, Wr0, Wth, Wtl);
    k_wsplit1<<<(80 * 256 + 255) / 256, 256, 0, stream>>>(Wl1, Wr1, Wt1h, Wt1l);
    k_xsplit<<<(Npad * 32) / 256, 256, 0, stream>>>(x, Xh, Xl, N);
    gemm0_mfma<<<(N + 63) / 64, 512, 0, stream>>>(Xh, Xl, Wth, Wtl, Yl, Yr, N);
    combine0<<<(N + 3) / 4, 256, 0, stream>>>(Yl, Yr, offs, ssrc, invc, bl0, Hh, Hl, N);
    k_wprep<<<(180 * 64 + 255) / 256, 256, 0, stream>>>(Wlin, Wb);   // after combine0 (Yr alias)
    gemm1_mfma<<<(numTiles + 3) / 4, 256, 0, stream>>>(Hh, Hl, Wt1h, Wt1l, Zl, Zr, N, numTiles);
    combine1<<<(N + 3) / 4, 256, 0, stream>>>(Zl, Zr, offs, ssrc, invc, bl1, H2, N);
    k_final_mfma<<<(N + 63) / 64, 256, 0, stream>>>(H2, Wb, blin, (float*)d_out, N);
}

// Round 13
// 453.502 us; speedup vs baseline: 1.0191x; 1.0191x over previous
//
#include <hip/hip_runtime.h>
#include <math.h>

// N=50000, F=256, H=256, C=40, E=800000; CURV=1, EPS=4e-3 -> maxnorm=0.996

typedef short bf16x8 __attribute__((ext_vector_type(8)));
typedef float f32x4 __attribute__((ext_vector_type(4)));

#define AS1 __attribute__((address_space(1)))
#define AS3 __attribute__((address_space(3)))

// pack two fp32 -> bf16x2 (round-half-up) : low short = a, high short = b
__device__ inline unsigned pack_bf16_hu(float a, float b) {
    unsigned ua = __float_as_uint(a) + 0x8000u;
    unsigned ub = __float_as_uint(b) + 0x8000u;
    return __builtin_amdgcn_perm(ub, ua, 0x07060302u);
}

__device__ inline unsigned short f2bf_rne(float x) {
    unsigned u = __float_as_uint(x);
    unsigned r = (u + 0x7fffu + ((u >> 16) & 1u)) >> 16;
    return (unsigned short)r;
}

// split (a,b) into hi bf16 pair + residual-lo bf16 pair (packed uints)
__device__ inline void split2(float a, float b, unsigned* hw, unsigned* lw) {
    unsigned ua = __float_as_uint(a) + 0x8000u;
    unsigned ub = __float_as_uint(b) + 0x8000u;
    *hw = __builtin_amdgcn_perm(ub, ua, 0x07060302u);
    float ra = a - __uint_as_float(ua & 0xFFFF0000u);
    float rb = b - __uint_as_float(ub & 0xFFFF0000u);
    unsigned va = __float_as_uint(ra) + 0x8000u;
    unsigned vb = __float_as_uint(rb) + 0x8000u;
    *lw = __builtin_amdgcn_perm(vb, va, 0x07060302u);
}

// ---------------- CSR build ----------------

__global__ void k_count(const int* __restrict__ dst, int* __restrict__ deg, int E) {
    int e = blockIdx.x * 256 + threadIdx.x;
    if (e < E) atomicAdd(&deg[dst[e]], 1);
}

__global__ __launch_bounds__(256) void k_scanA(const int* __restrict__ deg,
                                               int* __restrict__ offs,
                                               float* __restrict__ invc,
                                               int* __restrict__ bsum, int N) {
    __shared__ int wt[4];
    int tid = threadIdx.x, lane = tid & 63, wid = tid >> 6;
    int base = blockIdx.x * 1024 + tid * 4;
    int v[4];
    #pragma unroll
    for (int j = 0; j < 4; ++j) {
        int i = base + j;
        v[j] = (i < N) ? deg[i] : 0;
        if (i < N) invc[i] = 1.0f / (float)max(v[j], 1);
    }
    int t = v[0] + v[1] + v[2] + v[3];
    int s = t;
    #pragma unroll
    for (int d = 1; d < 64; d <<= 1) {
        int u = __shfl_up(s, d);
        if (lane >= d) s += u;
    }
    if (lane == 63) wt[wid] = s;
    __syncthreads();
    int wpre = 0, btot = 0;
    #pragma unroll
    for (int q = 0; q < 4; ++q) {
        int x = wt[q];
        btot += x;
        if (q < wid) wpre += x;
    }
    int run = wpre + s - t;
    #pragma unroll
    for (int j = 0; j < 4; ++j) {
        int i = base + j;
        if (i < N) offs[i] = run;
        run += v[j];
    }
    if (tid == 0) bsum[blockIdx.x] = btot;
}

__global__ __launch_bounds__(64) void k_scanB(int* __restrict__ bsum,
                                              int* __restrict__ offs, int N, int G) {
    int lane = threadIdx.x;
    int run = 0;
    for (int base = 0; base < G; base += 64) {
        int i = base + lane;
        int v = (i < G) ? bsum[i] : 0;
        int s = v;
        #pragma unroll
        for (int d = 1; d < 64; d <<= 1) {
            int u = __shfl_up(s, d);
            if (lane >= d) s += u;
        }
        int tot = __shfl(s, 63);
        if (i < G) bsum[i] = run + s - v;
        run += tot;
    }
    if (lane == 0) offs[N] = run;
}

__global__ __launch_bounds__(256) void k_scanC(int* __restrict__ offs,
                                               const int* __restrict__ bsum, int N) {
    int add = bsum[blockIdx.x];
    int base = blockIdx.x * 1024 + threadIdx.x * 4;
    #pragma unroll
    for (int j = 0; j < 4; ++j) {
        int i = base + j;
        if (i < N) offs[i] += add;
    }
}

__global__ void k_scatter(const int* __restrict__ src, const int* __restrict__ dst,
                          const int* __restrict__ offs, int* __restrict__ cursor,
                          int* __restrict__ ssrc, int E) {
    int e = blockIdx.x * 256 + threadIdx.x;
    if (e >= E) return;
    int d = dst[e];
    int pos = offs[d] + atomicAdd(&cursor[d], 1);
    ssrc[pos] = src[e];
}

// ---------------- weight prep ----------------
// k_wsplit0 v2: emits FRAGMENT-ORDERED Bf for gemm0.
// Bf[(w*8+g)*4+nf][lane][8] bf16: per-slot 64 lanes x 16B contiguous (1 KB wave load).

__global__ __launch_bounds__(256) void k_wsplit0(const float* __restrict__ Wl,
                                                 const float* __restrict__ Wr,
                                                 unsigned short* __restrict__ Bfh,
                                                 unsigned short* __restrict__ Bfl) {
    int idx = blockIdx.x * 256 + threadIdx.x;   // < 8*8*4*64 = 16384 lane-chunks
    int lane = idx & 63;
    int nf = (idx >> 6) & 3;
    int g  = (idx >> 8) & 7;
    int w  = (idx >> 11) & 7;
    int ml = lane & 15, quad = lane >> 4;
    int wc = w & 3;
    int n = (w < 4) ? (wc * 64 + (nf & 2) * 16 + 2 * ml + (nf & 1))
                    : (256 + wc * 64 + nf * 16 + ml);
    int kbase = g * 32 + quad * 8;
    unsigned short h8[8], l8[8];
    #pragma unroll
    for (int e = 0; e < 8; ++e) {
        int k = kbase + e;
        float v = (n < 256) ? Wl[k * 256 + n] : Wr[k * 256 + (n - 256)];
        unsigned short h = f2bf_rne(v);
        float hf = __uint_as_float(((unsigned)h) << 16);
        h8[e] = h;
        l8[e] = f2bf_rne(v - hf);
    }
    *(uint4*)&Bfh[(size_t)idx * 8] = *(uint4*)h8;
    *(uint4*)&Bfl[(size_t)idx * 8] = *(uint4*)l8;
}

__global__ __launch_bounds__(256) void k_wsplit1(const float* __restrict__ Wl,
                                                 const float* __restrict__ Wr,
                                                 unsigned short* __restrict__ Wth,
                                                 unsigned short* __restrict__ Wtl) {
    int idx = blockIdx.x * 256 + threadIdx.x;   // < 80*256
    if (idx >= 80 * 256) return;
    int n = idx >> 8, k = idx & 255;
    float v = (n < 40) ? Wl[k * 40 + n] : Wr[k * 40 + (n - 40)];
    unsigned short h = f2bf_rne(v);
    float hf = __uint_as_float(((unsigned)h) << 16);
    Wth[idx] = h;
    Wtl[idx] = f2bf_rne(v - hf);
}

// ---------------- X pre-split: X fp32 -> Xh/Xl bf16, chunk-XOR-swizzled rows ----------------

__global__ __launch_bounds__(256) void k_xsplit(const float* __restrict__ X,
                                                unsigned short* __restrict__ Xh,
                                                unsigned short* __restrict__ Xl,
                                                int N) {
    int idx = blockIdx.x * 256 + threadIdx.x;   // n*32 + c over Npad rows
    int n = idx >> 5, c = idx & 31;
    float4 v0 = make_float4(0.f, 0.f, 0.f, 0.f);
    float4 v1 = make_float4(0.f, 0.f, 0.f, 0.f);
    if (n < N) {
        v0 = *(const float4*)&X[(size_t)n * 256 + c * 8];
        v1 = *(const float4*)&X[(size_t)n * 256 + c * 8 + 4];
    }
    unsigned h0, l0, h1, l1, h2, l2, h3, l3;
    split2(v0.x, v0.y, &h0, &l0);
    split2(v0.z, v0.w, &h1, &l1);
    split2(v1.x, v1.y, &h2, &l2);
    split2(v1.z, v1.w, &h3, &l3);
    int cp = c ^ (n & 7);
    size_t o = (size_t)n * 256 + cp * 8;
    *(uint4*)&Xh[o] = make_uint4(h0, h1, h2, h3);
    *(uint4*)&Xl[o] = make_uint4(l0, l1, l2, l3);
}

// ---------------- gemm0 v8: single-buffered B + (512,4) -> 2 blocks/CU, no spill ----------------
// v7 post-mortem: (512,4) with B-dbuf spilled ~20 regs (WRITE 75->153MB). The dbuf costs
// 64 VGPR; single-buffering it brings unified regs to ~110 <= 128 -> clean 2 blocks/CU.
// Exposed per-group B latency (~200cyc L2) is hidden by the co-resident block's waves —
// the thing dbuf-at-1-block could never achieve. M=64 intensity unchanged (round-6 lesson).

__global__ __launch_bounds__(512, 4) void gemm0_mfma(const unsigned short* __restrict__ Xh,
                                                     const unsigned short* __restrict__ Xl,
                                                     const unsigned short* __restrict__ Bfh,
                                                     const unsigned short* __restrict__ Bfl,
                                                     unsigned short* __restrict__ Yl,
                                                     float* __restrict__ Yr, int N) {
    __shared__ __align__(16) unsigned short AhL[2][64 * 128];
    __shared__ __align__(16) unsigned short AlL[2][64 * 128];

    int tid = threadIdx.x;
    int lane = tid & 63;
    int w = __builtin_amdgcn_readfirstlane(tid >> 6);   // 0..7
    int ml = lane & 15, quad = lane >> 4;
    int m0 = blockIdx.x * 64;
    bool isYl = (w < 4);
    int wc = w & 3;

    // stage K-half h (256B/row) of rows m0..m0+63 -> linear LDS buffer h
    auto stage = [&](int h) {
        #pragma unroll
        for (int j = 0; j < 2; ++j) {
            int idx = j * 512 + tid;            // 0..1023 16B-chunks
            int row = idx >> 4, c16 = idx & 15;
            size_t gsrc = (size_t)(m0 + row) * 512 + (size_t)h * 256 + c16 * 16;
            int loff = idx * 16;
            __builtin_amdgcn_global_load_lds((const AS1 unsigned*)((const char*)Xh + gsrc),
                                             (AS3 unsigned*)((char*)&AhL[h][0] + loff), 16, 0, 0);
            __builtin_amdgcn_global_load_lds((const AS1 unsigned*)((const char*)Xl + gsrc),
                                             (AS3 unsigned*)((char*)&AlL[h][0] + loff), 16, 0, 0);
        }
    };

    stage(0);

    f32x4 acc[4][4];
    #pragma unroll
    for (int a = 0; a < 4; ++a)
        #pragma unroll
        for (int b = 0; b < 4; ++b) acc[a][b] = (f32x4){0.f, 0.f, 0.f, 0.f};

    __syncthreads();   // drains stage(0): half-0 ready (32KB, not 64KB)

    int swz = ml & 7;

    #pragma unroll
    for (int p = 0; p < 2; ++p) {
        if (p == 0) stage(1);               // half-1 in flight across half-0 compute
        const char* base_h = (const char*)&AhL[p][0];
        const char* base_l = (const char*)&AlL[p][0];
        #pragma unroll
        for (int g2 = 0; g2 < 4; ++g2) {
            int g = p * 4 + g2;
            // single-buffered fragment B: slot (w*8+g)*4+nf, per-lane 16B contiguous
            bf16x8 bh[4], bl[4];
            {
                size_t base = (((size_t)(w * 8 + g) * 4) * 64 + lane) * 8;
                #pragma unroll
                for (int nf = 0; nf < 4; ++nf) {
                    bh[nf] = *(const bf16x8*)&Bfh[base + (size_t)nf * 512];
                    bl[nf] = *(const bf16x8*)&Bfl[base + (size_t)nf * 512];
                }
            }
            bf16x8 ah[4], al[4];
            #pragma unroll
            for (int mf = 0; mf < 4; ++mf) {
                int ro = (mf * 16 + ml) * 256 + (((g2 * 4 + quad) ^ swz) * 16);
                ah[mf] = *(const bf16x8*)(base_h + ro);
                al[mf] = *(const bf16x8*)(base_l + ro);
            }
            #pragma unroll
            for (int nf = 0; nf < 4; ++nf)
                #pragma unroll
                for (int mf = 0; mf < 4; ++mf) {
                    acc[mf][nf] = __builtin_amdgcn_mfma_f32_16x16x32_bf16(ah[mf], bh[nf], acc[mf][nf], 0, 0, 0);
                    acc[mf][nf] = __builtin_amdgcn_mfma_f32_16x16x32_bf16(ah[mf], bl[nf], acc[mf][nf], 0, 0, 0);
                    acc[mf][nf] = __builtin_amdgcn_mfma_f32_16x16x32_bf16(al[mf], bh[nf], acc[mf][nf], 0, 0, 0);
                }
        }
        if (p == 0) __syncthreads();        // drains stage(1); all half-0 reads done
    }

    if (isYl) {
        #pragma unroll
        for (int mf = 0; mf < 4; ++mf)
            #pragma unroll
            for (int r = 0; r < 4; ++r) {
                int row = m0 + mf * 16 + quad * 4 + r;
                if (row < N) {
                    unsigned p0 = pack_bf16_hu(acc[mf][0][r], acc[mf][1][r]);
                    unsigned p1 = pack_bf16_hu(acc[mf][2][r], acc[mf][3][r]);
                    *(unsigned*)&Yl[(size_t)row * 256 + wc * 64 + 2 * ml] = p0;
                    *(unsigned*)&Yl[(size_t)row * 256 + wc * 64 + 32 + 2 * ml] = p1;
                }
            }
    } else {
        #pragma unroll
        for (int mf = 0; mf < 4; ++mf)
            #pragma unroll
            for (int r = 0; r < 4; ++r) {
                int row = m0 + mf * 16 + quad * 4 + r;
                if (row < N) {
                    #pragma unroll
                    for (int nf = 0; nf < 4; ++nf)
                        Yr[(size_t)row * 256 + wc * 64 + nf * 16 + ml] = acc[mf][nf][r];
                }
            }
    }
}

// ---------------- combine0 v3: 1 node/wave + 8-deep MLP + dense node-major H writes ----------------

__global__ __launch_bounds__(256) void combine0(const unsigned short* __restrict__ Yl,
                                                const float* __restrict__ Yr,
                                                const int* __restrict__ offs,
                                                const int* __restrict__ ssrc,
                                                const float* __restrict__ invc,
                                                const float* __restrict__ bl0,
                                                unsigned short* __restrict__ Hh,
                                                unsigned short* __restrict__ Hl, int N) {
    int wv = threadIdx.x >> 6, lane = threadIdx.x & 63;
    int n = blockIdx.x * 4 + wv;
    if (n >= N) return;
    int e0 = offs[n], e1 = offs[n + 1];
    float4 acc = make_float4(0.f, 0.f, 0.f, 0.f);
    int e = e0;
    for (; e + 7 < e1; e += 8) {
        int s0 = ssrc[e],     s1 = ssrc[e + 1], s2 = ssrc[e + 2], s3 = ssrc[e + 3];
        int s4 = ssrc[e + 4], s5 = ssrc[e + 5], s6 = ssrc[e + 6], s7 = ssrc[e + 7];
        uint2 p0 = *(const uint2*)&Yl[(size_t)s0 * 256 + lane * 4];
        uint2 p1 = *(const uint2*)&Yl[(size_t)s1 * 256 + lane * 4];
        uint2 p2 = *(const uint2*)&Yl[(size_t)s2 * 256 + lane * 4];
        uint2 p3 = *(const uint2*)&Yl[(size_t)s3 * 256 + lane * 4];
        uint2 p4 = *(const uint2*)&Yl[(size_t)s4 * 256 + lane * 4];
        uint2 p5 = *(const uint2*)&Yl[(size_t)s5 * 256 + lane * 4];
        uint2 p6 = *(const uint2*)&Yl[(size_t)s6 * 256 + lane * 4];
        uint2 p7 = *(const uint2*)&Yl[(size_t)s7 * 256 + lane * 4];
        acc.x += ((__uint_as_float(p0.x << 16) + __uint_as_float(p1.x << 16)) +
                  (__uint_as_float(p2.x << 16) + __uint_as_float(p3.x << 16))) +
                 ((__uint_as_float(p4.x << 16) + __uint_as_float(p5.x << 16)) +
                  (__uint_as_float(p6.x << 16) + __uint_as_float(p7.x << 16)));
        acc.y += ((__uint_as_float(p0.x & 0xFFFF0000u) + __uint_as_float(p1.x & 0xFFFF0000u)) +
                  (__uint_as_float(p2.x & 0xFFFF0000u) + __uint_as_float(p3.x & 0xFFFF0000u))) +
                 ((__uint_as_float(p4.x & 0xFFFF0000u) + __uint_as_float(p5.x & 0xFFFF0000u)) +
                  (__uint_as_float(p6.x & 0xFFFF0000u) + __uint_as_float(p7.x & 0xFFFF0000u)));
        acc.z += ((__uint_as_float(p0.y << 16) + __uint_as_float(p1.y << 16)) +
                  (__uint_as_float(p2.y << 16) + __uint_as_float(p3.y << 16))) +
                 ((__uint_as_float(p4.y << 16) + __uint_as_float(p5.y << 16)) +
                  (__uint_as_float(p6.y << 16) + __uint_as_float(p7.y << 16)));
        acc.w += ((__uint_as_float(p0.y & 0xFFFF0000u) + __uint_as_float(p1.y & 0xFFFF0000u)) +
                  (__uint_as_float(p2.y & 0xFFFF0000u) + __uint_as_float(p3.y & 0xFFFF0000u))) +
                 ((__uint_as_float(p4.y & 0xFFFF0000u) + __uint_as_float(p5.y & 0xFFFF0000u)) +
                  (__uint_as_float(p6.y & 0xFFFF0000u) + __uint_as_float(p7.y & 0xFFFF0000u)));
    }
    for (; e + 3 < e1; e += 4) {
        int s0 = ssrc[e], s1 = ssrc[e + 1], s2 = ssrc[e + 2], s3 = ssrc[e + 3];
        uint2 p = *(const uint2*)&Yl[(size_t)s0 * 256 + lane * 4];
        uint2 q = *(const uint2*)&Yl[(size_t)s1 * 256 + lane * 4];
        uint2 v = *(const uint2*)&Yl[(size_t)s2 * 256 + lane * 4];
        uint2 t = *(const uint2*)&Yl[(size_t)s3 * 256 + lane * 4];
        acc.x += (__uint_as_float(p.x << 16) + __uint_as_float(q.x << 16)) +
                 (__uint_as_float(v.x << 16) + __uint_as_float(t.x << 16));
        acc.y += (__uint_as_float(p.x & 0xFFFF0000u) + __uint_as_float(q.x & 0xFFFF0000u)) +
                 (__uint_as_float(v.x & 0xFFFF0000u) + __uint_as_float(t.x & 0xFFFF0000u));
        acc.z += (__uint_as_float(p.y << 16) + __uint_as_float(q.y << 16)) +
                 (__uint_as_float(v.y << 16) + __uint_as_float(t.y << 16));
        acc.w += (__uint_as_float(p.y & 0xFFFF0000u) + __uint_as_float(q.y & 0xFFFF0000u)) +
                 (__uint_as_float(v.y & 0xFFFF0000u) + __uint_as_float(t.y & 0xFFFF0000u));
    }
    for (; e < e1; ++e) {
        int s0 = ssrc[e];
        uint2 p = *(const uint2*)&Yl[(size_t)s0 * 256 + lane * 4];
        acc.x += __uint_as_float(p.x << 16);
        acc.y += __uint_as_float(p.x & 0xFFFF0000u);
        acc.z += __uint_as_float(p.y << 16);
        acc.w += __uint_as_float(p.y & 0xFFFF0000u);
    }
    float ic = invc[n];
    float4 b = *(const float4*)&bl0[lane * 4];
    float4 yr = *(const float4*)&Yr[(size_t)n * 256 + lane * 4];
    float hx = fmaxf(acc.x * ic + b.x + yr.x, 0.f);
    float hy = fmaxf(acc.y * ic + b.y + yr.y, 0.f);
    float hz = fmaxf(acc.z * ic + b.z + yr.z, 0.f);
    float hw = fmaxf(acc.w * ic + b.w + yr.w, 0.f);
    unsigned h0, h1, l0, l1;
    split2(hx, hy, &h0, &l0);
    split2(hz, hw, &h1, &l1);
    size_t offH = (size_t)n * 256 + lane * 4;   // node-major, fragment-k order: dense 512B/node
    *(uint2*)&Hh[offH] = make_uint2(h0, h1);
    *(uint2*)&Hl[offH] = make_uint2(l0, l1);
}

// ---------------- gemm1 v2: reads node-major fragment-k H layout ----------------

__global__ __launch_bounds__(256) void gemm1_mfma(const unsigned short* __restrict__ Hh,
                                                  const unsigned short* __restrict__ Hl,
                                                  const unsigned short* __restrict__ Bh,
                                                  const unsigned short* __restrict__ Bl,
                                                  unsigned short* __restrict__ Zl,
                                                  float* __restrict__ Zr, int N, int numTiles) {
    int tid = threadIdx.x;
    int lane = tid & 63;
    int w = __builtin_amdgcn_readfirstlane(tid >> 6);
    int ml = lane & 15, quad = lane >> 4;
    int t = blockIdx.x * 4 + w;
    if (t >= numTiles) return;

    const unsigned short* ahp = Hh + (size_t)(t * 16 + ml) * 256 + quad * 8;
    const unsigned short* alp = Hl + (size_t)(t * 16 + ml) * 256 + quad * 8;

    f32x4 acc[5];
    #pragma unroll
    for (int b = 0; b < 5; ++b) acc[b] = (f32x4){0.f, 0.f, 0.f, 0.f};

    #pragma unroll
    for (int kc = 0; kc < 8; ++kc) {
        bf16x8 ah = *(const bf16x8*)&ahp[kc * 32];
        bf16x8 al = *(const bf16x8*)&alp[kc * 32];
        int ko = kc * 32 + quad * 8;
        #pragma unroll
        for (int nf = 0; nf < 5; ++nf) {
            size_t bo = (size_t)(nf * 16 + ml) * 256 + ko;
            bf16x8 bh = *(const bf16x8*)&Bh[bo];
            bf16x8 bl = *(const bf16x8*)&Bl[bo];
            acc[nf] = __builtin_amdgcn_mfma_f32_16x16x32_bf16(ah, bh, acc[nf], 0, 0, 0);
            acc[nf] = __builtin_amdgcn_mfma_f32_16x16x32_bf16(ah, bl, acc[nf], 0, 0, 0);
            acc[nf] = __builtin_amdgcn_mfma_f32_16x16x32_bf16(al, bh, acc[nf], 0, 0, 0);
        }
    }
    #pragma unroll
    for (int r = 0; r < 4; ++r) {
        int n = t * 16 + quad * 4 + r;
        if (n < N) {
            #pragma unroll
            for (int nf = 0; nf < 5; ++nf) {
                int col = nf * 16 + ml;
                if (col < 40) Zl[(size_t)n * 40 + col] = f2bf_rne(acc[nf][r]);
                else Zr[(size_t)n * 40 + (col - 40)] = acc[nf][r];
            }
        }
    }
}

// ---------------- combine1: bf16 Zl gather ----------------

__global__ __launch_bounds__(256) void combine1(const unsigned short* __restrict__ Zl,
                                                const float* __restrict__ Zr,
                                                const int* __restrict__ offs,
                                                const int* __restrict__ ssrc,
                                                const float* __restrict__ invc,
                                                const float* __restrict__ bl1,
                                                float* __restrict__ H2, int N) {
    int wv = threadIdx.x >> 6, lane = threadIdx.x & 63;
    int n = blockIdx.x * 4 + wv;
    if (n >= N) return;
    if (lane >= 40) return;
    int e0 = offs[n], e1 = offs[n + 1];
    float acc = 0.f;
    int e = e0;
    for (; e + 1 < e1; e += 2) {
        int s0 = ssrc[e], s1 = ssrc[e + 1];
        unsigned a = Zl[(size_t)s0 * 40 + lane];
        unsigned b = Zl[(size_t)s1 * 40 + lane];
        acc += __uint_as_float(a << 16) + __uint_as_float(b << 16);
    }
    if (e < e1) {
        unsigned a = Zl[(size_t)ssrc[e] * 40 + lane];
        acc += __uint_as_float(a << 16);
    }
    float v = acc * invc[n] + bl1[lane] + Zr[(size_t)n * 40 + lane];
    H2[(size_t)n * 40 + lane] = v;
}

// ---------------- W_lin pre-convert v2: fragment-ordered WbF ----------------
// WbF[slot][lane][8] bf16, slot = (c*3+s)*3+cf (c=0..19, s=0..2, cf=0..2), lane=0..63.

__global__ __launch_bounds__(256) void k_wprep(const float* __restrict__ W,
                                               unsigned short* __restrict__ WbF) {
    int idx = blockIdx.x * 256 + threadIdx.x;   // chunk index < 180*64
    if (idx >= 180 * 64) return;
    int slot = idx >> 6, lane = idx & 63;
    int cf = slot % 3;
    int cs = slot / 3;
    int s = cs % 3;
    int c = cs / 3;
    int ml = lane & 15, quad = lane >> 4;
    int col = cf * 16 + ml;
    int kbase = c * 96 + s * 32 + quad * 8;
    unsigned short v8[8];
    #pragma unroll
    for (int e = 0; e < 8; ++e) {
        int kp = kbase + e;
        int i = kp / 48;
        int j = kp - i * 48;
        float v = 0.f;
        if (col < 40 && i < 40 && j < 40) v = W[((size_t)(i * 40 + j)) * 40 + col];
        v8[e] = f2bf_rne(v);
    }
    *(uint4*)&WbF[(size_t)idx * 8] = *(uint4*)v8;
}

// ---------------- k_final_mfma v4: register windows + coalesced WbF + free VGPR budget ----

__global__ __launch_bounds__(256, 1) void k_final_mfma(const float* __restrict__ H2,
                                                       const unsigned short* __restrict__ WbF,
                                                       const float* __restrict__ blin,
                                                       float* __restrict__ out, int N) {
    int tid = threadIdx.x;
    int m0 = blockIdx.x * 64;
    int lane = tid & 63;
    int w = __builtin_amdgcn_readfirstlane(tid >> 6);
    int ml = lane & 15;
    int quad = lane >> 4;
    int row = w * 16 + ml;
    int gn = m0 + row;

    float g[48];
    float s2 = 0.f;
    #pragma unroll
    for (int q4 = 0; q4 < 10; ++q4) {
        float4 v = make_float4(0.f, 0.f, 0.f, 0.f);
        if (gn < N) v = *(const float4*)&H2[(size_t)gn * 40 + q4 * 4];
        g[q4 * 4 + 0] = v.x; g[q4 * 4 + 1] = v.y;
        g[q4 * 4 + 2] = v.z; g[q4 * 4 + 3] = v.w;
        s2 += v.x * v.x + v.y * v.y + v.z * v.z + v.w * v.w;
    }
    #pragma unroll
    for (int j = 40; j < 48; ++j) g[j] = 0.f;

    float aln = atanhf(fminf(fmaxf(s2, 1e-15f), 0.996f)) / fmaxf(s2, 1e-30f);

    bool isQ0 = (quad == 0), isQ2 = (quad == 2), qLo = (quad < 2);
    float wA[8], wB[8], wC[8];
    #pragma unroll
    for (int j = 0; j < 8; ++j) {
        float a0 = isQ0 ? g[j] : g[8 + j];
        float a1 = isQ2 ? g[16 + j] : g[24 + j];
        wA[j] = qLo ? a0 : a1;
        float b0 = isQ0 ? g[32 + j] : g[40 + j];
        float b1 = isQ2 ? g[j] : g[8 + j];
        wB[j] = qLo ? b0 : b1;
        float c0 = isQ0 ? g[16 + j] : g[24 + j];
        float c1 = isQ2 ? g[32 + j] : g[40 + j];
        wC[j] = qLo ? c0 : c1;
    }

    f32x4 acc[3];
    #pragma unroll
    for (int c = 0; c < 3; ++c) acc[c] = (f32x4){0.f, 0.f, 0.f, 0.f};

    const unsigned short* bw = WbF + (size_t)lane * 8;

    #pragma unroll
    for (int c = 0; c < 20; ++c) {
        float gi0 = g[2 * c];
        float gi1 = qLo ? g[2 * c] : g[2 * c + 1];
        float gi2 = g[2 * c + 1];
        {
            const int slot = (c * 3 + 0) * 3;
            union { unsigned u[4]; bf16x8 v; } A;
            A.u[0] = pack_bf16_hu(gi0 * wA[0], gi0 * wA[1]);
            A.u[1] = pack_bf16_hu(gi0 * wA[2], gi0 * wA[3]);
            A.u[2] = pack_bf16_hu(gi0 * wA[4], gi0 * wA[5]);
            A.u[3] = pack_bf16_hu(gi0 * wA[6], gi0 * wA[7]);
            #pragma unroll
            for (int cf = 0; cf < 3; ++cf) {
                bf16x8 bf = *(const bf16x8*)&bw[(size_t)(slot + cf) * 512];
                acc[cf] = __builtin_amdgcn_mfma_f32_16x16x32_bf16(A.v, bf, acc[cf], 0, 0, 0);
            }
        }
        {
            const int slot = (c * 3 + 1) * 3;
            union { unsigned u[4]; bf16x8 v; } A;
            A.u[0] = pack_bf16_hu(gi1 * wB[0], gi1 * wB[1]);
            A.u[1] = pack_bf16_hu(gi1 * wB[2], gi1 * wB[3]);
            A.u[2] = pack_bf16_hu(gi1 * wB[4], gi1 * wB[5]);
            A.u[3] = pack_bf16_hu(gi1 * wB[6], gi1 * wB[7]);
            #pragma unroll
            for (int cf = 0; cf < 3; ++cf) {
                bf16x8 bf = *(const bf16x8*)&bw[(size_t)(slot + cf) * 512];
                acc[cf] = __builtin_amdgcn_mfma_f32_16x16x32_bf16(A.v, bf, acc[cf], 0, 0, 0);
            }
        }
        {
            const int slot = (c * 3 + 2) * 3;
            union { unsigned u[4]; bf16x8 v; } A;
            A.u[0] = pack_bf16_hu(gi2 * wC[0], gi2 * wC[1]);
            A.u[1] = pack_bf16_hu(gi2 * wC[2], gi2 * wC[3]);
            A.u[2] = pack_bf16_hu(gi2 * wC[4], gi2 * wC[5]);
            A.u[3] = pack_bf16_hu(gi2 * wC[6], gi2 * wC[7]);
            #pragma unroll
            for (int cf = 0; cf < 3; ++cf) {
                bf16x8 bf = *(const bf16x8*)&bw[(size_t)(slot + cf) * 512];
                acc[cf] = __builtin_amdgcn_mfma_f32_16x16x32_bf16(A.v, bf, acc[cf], 0, 0, 0);
            }
        }
    }

    float bcol[3];
    #pragma unroll
    for (int c = 0; c < 3; ++c) {
        int col = c * 16 + ml;
        bcol[c] = (col < 40) ? blin[col] : 0.f;
    }
    bool v2 = (ml < 8);

    #pragma unroll
    for (int r = 0; r < 4; ++r) {
        int nloc = w * 16 + quad * 4 + r;
        float al = __shfl(aln, quad * 4 + r);
        float u0 = al * acc[0][r] + bcol[0];
        float u1 = al * acc[1][r] + bcol[1];
        float u2 = v2 ? (al * acc[2][r] + bcol[2]) : 0.f;
        float un2 = u0 * u0 + u1 * u1 + u2 * u2;
        #pragma unroll
        for (int m = 1; m < 16; m <<= 1) un2 += __shfl_xor(un2, m);
        float un = fmaxf(sqrtf(un2), 1e-15f);
        float tnh = tanhf(un);
        float gma = tnh / un;
        float ps = (tnh > 0.996f) ? (0.996f / tnh) : 1.0f;
        float s = gma * ps;
        float l0 = s * u0, l1 = s * u1, l2 = s * u2;
        float mx = fmaxf(l0, l1);
        if (v2) mx = fmaxf(mx, l2);
        #pragma unroll
        for (int m = 1; m < 16; m <<= 1) mx = fmaxf(mx, __shfl_xor(mx, m));
        float se = expf(l0 - mx) + expf(l1 - mx) + (v2 ? expf(l2 - mx) : 0.f);
        #pragma unroll
        for (int m = 1; m < 16; m <<= 1) se += __shfl_xor(se, m);
        float lse = logf(se);
        int go = m0 + nloc;
        if (go < N) {
            out[(size_t)go * 40 + ml] = l0 - mx - lse;
            out[(size_t)go * 40 + 16 + ml] = l1 - mx - lse;
            if (v2) out[(size_t)go * 40 + 32 + ml] = l2 - mx - lse;
        }
    }
}

// ---------------- launch ----------------

extern "C" void kernel_launch(void* const* d_in, const int* in_sizes, int n_in,
                              void* d_out, int out_size, void* d_ws, size_t ws_size,
                              hipStream_t stream) {
    const float* x    = (const float*)d_in[0];
    const int*   ei   = (const int*)d_in[1];
    const float* Wl0  = (const float*)d_in[2];
    const float* bl0  = (const float*)d_in[3];
    const float* Wr0  = (const float*)d_in[4];
    const float* Wl1  = (const float*)d_in[5];
    const float* bl1  = (const float*)d_in[6];
    const float* Wr1  = (const float*)d_in[7];
    const float* Wlin = (const float*)d_in[8];
    const float* blin = (const float*)d_in[9];
    int N = in_sizes[0] / 256;
    int E = in_sizes[1] / 2;
    const int* src = ei;
    const int* dst = ei + E;
    int numTiles = (N + 15) / 16;
    int Npad = ((N + 63) / 64) * 64;          // gemm0 tile-padded row count

    char* ws = (char*)d_ws;
    size_t off = 0;
    auto carve = [&](size_t bytes) -> char* {
        char* p = ws + off;
        off = (off + bytes + 255) & ~(size_t)255;
        return p;
    };
    size_t xbytes = (size_t)Npad * 256 * 2;   // >= numTiles*4096*2
    int*   deg    = (int*)carve((size_t)N * 4);
    int*   cursor = (int*)carve((size_t)N * 4);
    int*   offs   = (int*)carve((size_t)(N + 1) * 4);
    float* invc   = (float*)carve((size_t)N * 4);
    int*   bsum   = (int*)carve(1024);
    int*   ssrc   = (int*)carve((size_t)E * 4);
    unsigned short* Yl = (unsigned short*)carve((size_t)N * 256 * 2);
    float* Yr     = (float*)carve((size_t)N * 256 * 4);
    unsigned short* Hh = (unsigned short*)carve(xbytes);
    unsigned short* Hl = (unsigned short*)carve(xbytes);
    unsigned short* Zl = (unsigned short*)carve((size_t)N * 40 * 2);
    float* Zr     = (float*)carve((size_t)N * 40 * 4);
    float* H2     = (float*)carve((size_t)N * 40 * 4);
    // Xh/Xl (pre-split, swizzled X) alias Hh/Hl: dead before combine0 writes Hh/Hl
    unsigned short* Xh = Hh;
    unsigned short* Xl = Hl;
    // WbF (180*64*8 bf16 = 184 KB) aliases Yr (dead after combine0)
    unsigned short* Wb = (unsigned short*)Yr;
    // split weights alias H2 (written only at combine1, after gemm1)
    unsigned short* Wth  = (unsigned short*)H2;    // gemm0 fragment B: 256 KB
    unsigned short* Wtl  = Wth + 512 * 256;        // 256 KB
    unsigned short* Wt1h = Wtl + 512 * 256;
    unsigned short* Wt1l = Wt1h + 80 * 256;

    int G = (N + 1023) / 1024;

    hipMemsetAsync(deg, 0, (size_t)N * 4, stream);
    hipMemsetAsync(cursor, 0, (size_t)N * 4, stream);

    k_count<<<(E + 255) / 256, 256, 0, stream>>>(dst, deg, E);
    k_scanA<<<G, 256, 0, stream>>>(deg, offs, invc, bsum, N);
    k_scanB<<<1, 64, 0, stream>>>(bsum, offs, N, G);
    k_scanC<<<G, 256, 0, stream>>>(offs, bsum, N);
    k_scatter<<<(E + 255) / 256, 256, 0, stream>>>(src, dst, offs, cursor, ssrc, E);
    k_wsplit0<<<64, 256, 0, stream>>>(Wl0, Wr0, Wth, Wtl);
    k_wsplit1<<<(80 * 256 + 255) / 256, 256, 0, stream>>>(Wl1, Wr1, Wt1h, Wt1l);
    k_xsplit<<<(Npad * 32) / 256, 256, 0, stream>>>(x, Xh, Xl, N);
    gemm0_mfma<<<(N + 63) / 64, 512, 0, stream>>>(Xh, Xl, Wth, Wtl, Yl, Yr, N);
    combine0<<<(N + 3) / 4, 256, 0, stream>>>(Yl, Yr, offs, ssrc, invc, bl0, Hh, Hl, N);
    k_wprep<<<(180 * 64 + 255) / 256, 256, 0, stream>>>(Wlin, Wb);   // after combine0 (Yr alias)
    gemm1_mfma<<<(numTiles + 3) / 4, 256, 0, stream>>>(Hh, Hl, Wt1h, Wt1l, Zl, Zr, N, numTiles);
    combine1<<<(N + 3) / 4, 256, 0, stream>>>(Zl, Zr, offs, ssrc, invc, bl1, H2, N);
    k_final_mfma<<<(N + 63) / 64, 256, 0, stream>>>(H2, Wb, blin, (float*)d_out, N);
}

// Round 14
// 422.015 us; speedup vs baseline: 1.0952x; 1.0746x over previous
//
#include <hip/hip_runtime.h>
#include <math.h>

// N=50000, F=256, H=256, C=40, E=800000; CURV=1, EPS=4e-3 -> maxnorm=0.996

typedef short bf16x8 __attribute__((ext_vector_type(8)));
typedef float f32x4 __attribute__((ext_vector_type(4)));

#define AS1 __attribute__((address_space(1)))
#define AS3 __attribute__((address_space(3)))

// pack two fp32 -> bf16x2 (round-half-up) : low short = a, high short = b
__device__ inline unsigned pack_bf16_hu(float a, float b) {
    unsigned ua = __float_as_uint(a) + 0x8000u;
    unsigned ub = __float_as_uint(b) + 0x8000u;
    return __builtin_amdgcn_perm(ub, ua, 0x07060302u);
}

__device__ inline unsigned short f2bf_rne(float x) {
    unsigned u = __float_as_uint(x);
    unsigned r = (u + 0x7fffu + ((u >> 16) & 1u)) >> 16;
    return (unsigned short)r;
}

// split (a,b) into hi bf16 pair + residual-lo bf16 pair (packed uints)
__device__ inline void split2(float a, float b, unsigned* hw, unsigned* lw) {
    unsigned ua = __float_as_uint(a) + 0x8000u;
    unsigned ub = __float_as_uint(b) + 0x8000u;
    *hw = __builtin_amdgcn_perm(ub, ua, 0x07060302u);
    float ra = a - __uint_as_float(ua & 0xFFFF0000u);
    float rb = b - __uint_as_float(ub & 0xFFFF0000u);
    unsigned va = __float_as_uint(ra) + 0x8000u;
    unsigned vb = __float_as_uint(rb) + 0x8000u;
    *lw = __builtin_amdgcn_perm(vb, va, 0x07060302u);
}

// ---------------- CSR build ----------------

__global__ void k_count(const int* __restrict__ dst, int* __restrict__ deg, int E) {
    int e = blockIdx.x * 256 + threadIdx.x;
    if (e < E) atomicAdd(&deg[dst[e]], 1);
}

__global__ __launch_bounds__(256) void k_scanA(const int* __restrict__ deg,
                                               int* __restrict__ offs,
                                               float* __restrict__ invc,
                                               int* __restrict__ bsum, int N) {
    __shared__ int wt[4];
    int tid = threadIdx.x, lane = tid & 63, wid = tid >> 6;
    int base = blockIdx.x * 1024 + tid * 4;
    int v[4];
    #pragma unroll
    for (int j = 0; j < 4; ++j) {
        int i = base + j;
        v[j] = (i < N) ? deg[i] : 0;
        if (i < N) invc[i] = 1.0f / (float)max(v[j], 1);
    }
    int t = v[0] + v[1] + v[2] + v[3];
    int s = t;
    #pragma unroll
    for (int d = 1; d < 64; d <<= 1) {
        int u = __shfl_up(s, d);
        if (lane >= d) s += u;
    }
    if (lane == 63) wt[wid] = s;
    __syncthreads();
    int wpre = 0, btot = 0;
    #pragma unroll
    for (int q = 0; q < 4; ++q) {
        int x = wt[q];
        btot += x;
        if (q < wid) wpre += x;
    }
    int run = wpre + s - t;
    #pragma unroll
    for (int j = 0; j < 4; ++j) {
        int i = base + j;
        if (i < N) offs[i] = run;
        run += v[j];
    }
    if (tid == 0) bsum[blockIdx.x] = btot;
}

__global__ __launch_bounds__(64) void k_scanB(int* __restrict__ bsum,
                                              int* __restrict__ offs, int N, int G) {
    int lane = threadIdx.x;
    int run = 0;
    for (int base = 0; base < G; base += 64) {
        int i = base + lane;
        int v = (i < G) ? bsum[i] : 0;
        int s = v;
        #pragma unroll
        for (int d = 1; d < 64; d <<= 1) {
            int u = __shfl_up(s, d);
            if (lane >= d) s += u;
        }
        int tot = __shfl(s, 63);
        if (i < G) bsum[i] = run + s - v;
        run += tot;
    }
    if (lane == 0) offs[N] = run;
}

__global__ __launch_bounds__(256) void k_scanC(int* __restrict__ offs,
                                               const int* __restrict__ bsum, int N) {
    int add = bsum[blockIdx.x];
    int base = blockIdx.x * 1024 + threadIdx.x * 4;
    #pragma unroll
    for (int j = 0; j < 4; ++j) {
        int i = base + j;
        if (i < N) offs[i] += add;
    }
}

__global__ void k_scatter(const int* __restrict__ src, const int* __restrict__ dst,
                          const int* __restrict__ offs, int* __restrict__ cursor,
                          int* __restrict__ ssrc, int E) {
    int e = blockIdx.x * 256 + threadIdx.x;
    if (e >= E) return;
    int d = dst[e];
    int pos = offs[d] + atomicAdd(&cursor[d], 1);
    ssrc[pos] = src[e];
}

// ---------------- weight prep ----------------
// k_wsplit0 v2: emits FRAGMENT-ORDERED Bf for gemm0.
// Bf[(w*8+g)*4+nf][lane][8] bf16: per-slot 64 lanes x 16B contiguous (1 KB wave load).

__global__ __launch_bounds__(256) void k_wsplit0(const float* __restrict__ Wl,
                                                 const float* __restrict__ Wr,
                                                 unsigned short* __restrict__ Bfh,
                                                 unsigned short* __restrict__ Bfl) {
    int idx = blockIdx.x * 256 + threadIdx.x;   // < 8*8*4*64 = 16384 lane-chunks
    int lane = idx & 63;
    int nf = (idx >> 6) & 3;
    int g  = (idx >> 8) & 7;
    int w  = (idx >> 11) & 7;
    int ml = lane & 15, quad = lane >> 4;
    int wc = w & 3;
    int n = (w < 4) ? (wc * 64 + (nf & 2) * 16 + 2 * ml + (nf & 1))
                    : (256 + wc * 64 + nf * 16 + ml);
    int kbase = g * 32 + quad * 8;
    unsigned short h8[8], l8[8];
    #pragma unroll
    for (int e = 0; e < 8; ++e) {
        int k = kbase + e;
        float v = (n < 256) ? Wl[k * 256 + n] : Wr[k * 256 + (n - 256)];
        unsigned short h = f2bf_rne(v);
        float hf = __uint_as_float(((unsigned)h) << 16);
        h8[e] = h;
        l8[e] = f2bf_rne(v - hf);
    }
    *(uint4*)&Bfh[(size_t)idx * 8] = *(uint4*)h8;
    *(uint4*)&Bfl[(size_t)idx * 8] = *(uint4*)l8;
}

// k_wsplit1 v2: FRAGMENT-ORDERED Bf1 for gemm1 (3rd application of the pattern).
// Bf1[kc*5+nf][lane][8] bf16: slot stream is 40 KB (h) + 40 KB (l), shared by all
// waves -> contiguous 1 KB wave loads, L2-resident broadcast.
// n = nf*16+ml (<80), k = kc*32+quad*8+e.

__global__ __launch_bounds__(256) void k_wsplit1(const float* __restrict__ Wl,
                                                 const float* __restrict__ Wr,
                                                 unsigned short* __restrict__ Bfh,
                                                 unsigned short* __restrict__ Bfl) {
    int idx = blockIdx.x * 256 + threadIdx.x;   // < 40*64 = 2560 lane-chunks
    if (idx >= 40 * 64) return;
    int lane = idx & 63;
    int slot = idx >> 6;        // 0..39
    int nf = slot % 5;
    int kc = slot / 5;
    int ml = lane & 15, quad = lane >> 4;
    int n = nf * 16 + ml;
    int kbase = kc * 32 + quad * 8;
    unsigned short h8[8], l8[8];
    #pragma unroll
    for (int e = 0; e < 8; ++e) {
        int k = kbase + e;
        float v = (n < 40) ? Wl[k * 40 + n] : Wr[k * 40 + (n - 40)];
        unsigned short h = f2bf_rne(v);
        float hf = __uint_as_float(((unsigned)h) << 16);
        h8[e] = h;
        l8[e] = f2bf_rne(v - hf);
    }
    *(uint4*)&Bfh[(size_t)idx * 8] = *(uint4*)h8;
    *(uint4*)&Bfl[(size_t)idx * 8] = *(uint4*)l8;
}

// ---------------- X pre-split: X fp32 -> Xh/Xl bf16, chunk-XOR-swizzled rows ----------------

__global__ __launch_bounds__(256) void k_xsplit(const float* __restrict__ X,
                                                unsigned short* __restrict__ Xh,
                                                unsigned short* __restrict__ Xl,
                                                int N) {
    int idx = blockIdx.x * 256 + threadIdx.x;   // n*32 + c over Npad rows
    int n = idx >> 5, c = idx & 31;
    float4 v0 = make_float4(0.f, 0.f, 0.f, 0.f);
    float4 v1 = make_float4(0.f, 0.f, 0.f, 0.f);
    if (n < N) {
        v0 = *(const float4*)&X[(size_t)n * 256 + c * 8];
        v1 = *(const float4*)&X[(size_t)n * 256 + c * 8 + 4];
    }
    unsigned h0, l0, h1, l1, h2, l2, h3, l3;
    split2(v0.x, v0.y, &h0, &l0);
    split2(v0.z, v0.w, &h1, &l1);
    split2(v1.x, v1.y, &h2, &l2);
    split2(v1.z, v1.w, &h3, &l3);
    int cp = c ^ (n & 7);
    size_t o = (size_t)n * 256 + cp * 8;
    *(uint4*)&Xh[o] = make_uint4(h0, h1, h2, h3);
    *(uint4*)&Xl[o] = make_uint4(l0, l1, l2, l3);
}

// ---------------- gemm0 v6 (REVERTED, round-11 best): M=64, fragment dbuf B, 2-phase stage ----
// Occupancy experiments R6/R12/R13 all lost to this config: dbuf-B + 1 block/CU +
// 2-phase K-half staging is gemm0's empirical optimum. Do not re-litigate.

__global__ __launch_bounds__(512) void gemm0_mfma(const unsigned short* __restrict__ Xh,
                                                  const unsigned short* __restrict__ Xl,
                                                  const unsigned short* __restrict__ Bfh,
                                                  const unsigned short* __restrict__ Bfl,
                                                  unsigned short* __restrict__ Yl,
                                                  float* __restrict__ Yr, int N) {
    __shared__ __align__(16) unsigned short AhL[2][64 * 128];
    __shared__ __align__(16) unsigned short AlL[2][64 * 128];

    int tid = threadIdx.x;
    int lane = tid & 63;
    int w = __builtin_amdgcn_readfirstlane(tid >> 6);   // 0..7
    int ml = lane & 15, quad = lane >> 4;
    int m0 = blockIdx.x * 64;
    bool isYl = (w < 4);
    int wc = w & 3;

    // stage K-half h (256B/row) of rows m0..m0+63 -> linear LDS buffer h
    auto stage = [&](int h) {
        #pragma unroll
        for (int j = 0; j < 2; ++j) {
            int idx = j * 512 + tid;            // 0..1023 16B-chunks
            int row = idx >> 4, c16 = idx & 15;
            size_t gsrc = (size_t)(m0 + row) * 512 + (size_t)h * 256 + c16 * 16;
            int loff = idx * 16;
            __builtin_amdgcn_global_load_lds((const AS1 unsigned*)((const char*)Xh + gsrc),
                                             (AS3 unsigned*)((char*)&AhL[h][0] + loff), 16, 0, 0);
            __builtin_amdgcn_global_load_lds((const AS1 unsigned*)((const char*)Xl + gsrc),
                                             (AS3 unsigned*)((char*)&AlL[h][0] + loff), 16, 0, 0);
        }
    };

    stage(0);

    f32x4 acc[4][4];
    #pragma unroll
    for (int a = 0; a < 4; ++a)
        #pragma unroll
        for (int b = 0; b < 4; ++b) acc[a][b] = (f32x4){0.f, 0.f, 0.f, 0.f};

    bf16x8 bh0[4], bl0[4], bh1[4], bl1[4];

    // fragment-ordered B: slot (w*8+g)*4+nf, per-lane 16B contiguous
    auto loadB = [&](int it, bf16x8* bh, bf16x8* bl) {
        size_t base = (((size_t)(w * 8 + it) * 4) * 64 + lane) * 8;
        #pragma unroll
        for (int nf = 0; nf < 4; ++nf) {
            bh[nf] = *(const bf16x8*)&Bfh[base + (size_t)nf * 512];
            bl[nf] = *(const bf16x8*)&Bfl[base + (size_t)nf * 512];
        }
    };

    loadB(0, bh0, bl0);
    __syncthreads();   // drains stage(0): half-0 ready (32KB, not 64KB)

    int swz = ml & 7;

    #pragma unroll
    for (int p = 0; p < 2; ++p) {
        if (p == 0) stage(1);               // half-1 in flight across half-0 compute
        const char* base_h = (const char*)&AhL[p][0];
        const char* base_l = (const char*)&AlL[p][0];
        #pragma unroll
        for (int g2 = 0; g2 < 4; ++g2) {
            int g = p * 4 + g2;
            bf16x8* bhc = (g & 1) ? bh1 : bh0;
            bf16x8* blc = (g & 1) ? bl1 : bl0;
            bf16x8* bhn = (g & 1) ? bh0 : bh1;
            bf16x8* bln = (g & 1) ? bl0 : bl1;
            if (g < 7) loadB(g + 1, bhn, bln);
            bf16x8 ah[4], al[4];
            #pragma unroll
            for (int mf = 0; mf < 4; ++mf) {
                int ro = (mf * 16 + ml) * 256 + (((g2 * 4 + quad) ^ swz) * 16);
                ah[mf] = *(const bf16x8*)(base_h + ro);
                al[mf] = *(const bf16x8*)(base_l + ro);
            }
            #pragma unroll
            for (int nf = 0; nf < 4; ++nf)
                #pragma unroll
                for (int mf = 0; mf < 4; ++mf) {
                    acc[mf][nf] = __builtin_amdgcn_mfma_f32_16x16x32_bf16(ah[mf], bhc[nf], acc[mf][nf], 0, 0, 0);
                    acc[mf][nf] = __builtin_amdgcn_mfma_f32_16x16x32_bf16(ah[mf], blc[nf], acc[mf][nf], 0, 0, 0);
                    acc[mf][nf] = __builtin_amdgcn_mfma_f32_16x16x32_bf16(al[mf], bhc[nf], acc[mf][nf], 0, 0, 0);
                }
        }
        if (p == 0) __syncthreads();        // drains stage(1); all half-0 reads done
    }

    if (isYl) {
        #pragma unroll
        for (int mf = 0; mf < 4; ++mf)
            #pragma unroll
            for (int r = 0; r < 4; ++r) {
                int row = m0 + mf * 16 + quad * 4 + r;
                if (row < N) {
                    unsigned p0 = pack_bf16_hu(acc[mf][0][r], acc[mf][1][r]);
                    unsigned p1 = pack_bf16_hu(acc[mf][2][r], acc[mf][3][r]);
                    *(unsigned*)&Yl[(size_t)row * 256 + wc * 64 + 2 * ml] = p0;
                    *(unsigned*)&Yl[(size_t)row * 256 + wc * 64 + 32 + 2 * ml] = p1;
                }
            }
    } else {
        #pragma unroll
        for (int mf = 0; mf < 4; ++mf)
            #pragma unroll
            for (int r = 0; r < 4; ++r) {
                int row = m0 + mf * 16 + quad * 4 + r;
                if (row < N) {
                    #pragma unroll
                    for (int nf = 0; nf < 4; ++nf)
                        Yr[(size_t)row * 256 + wc * 64 + nf * 16 + ml] = acc[mf][nf][r];
                }
            }
    }
}

// ---------------- combine0 v3: 1 node/wave + 8-deep MLP + dense node-major H writes ----------------

__global__ __launch_bounds__(256) void combine0(const unsigned short* __restrict__ Yl,
                                                const float* __restrict__ Yr,
                                                const int* __restrict__ offs,
                                                const int* __restrict__ ssrc,
                                                const float* __restrict__ invc,
                                                const float* __restrict__ bl0,
                                                unsigned short* __restrict__ Hh,
                                                unsigned short* __restrict__ Hl, int N) {
    int wv = threadIdx.x >> 6, lane = threadIdx.x & 63;
    int n = blockIdx.x * 4 + wv;
    if (n >= N) return;
    int e0 = offs[n], e1 = offs[n + 1];
    float4 acc = make_float4(0.f, 0.f, 0.f, 0.f);
    int e = e0;
    for (; e + 7 < e1; e += 8) {
        int s0 = ssrc[e],     s1 = ssrc[e + 1], s2 = ssrc[e + 2], s3 = ssrc[e + 3];
        int s4 = ssrc[e + 4], s5 = ssrc[e + 5], s6 = ssrc[e + 6], s7 = ssrc[e + 7];
        uint2 p0 = *(const uint2*)&Yl[(size_t)s0 * 256 + lane * 4];
        uint2 p1 = *(const uint2*)&Yl[(size_t)s1 * 256 + lane * 4];
        uint2 p2 = *(const uint2*)&Yl[(size_t)s2 * 256 + lane * 4];
        uint2 p3 = *(const uint2*)&Yl[(size_t)s3 * 256 + lane * 4];
        uint2 p4 = *(const uint2*)&Yl[(size_t)s4 * 256 + lane * 4];
        uint2 p5 = *(const uint2*)&Yl[(size_t)s5 * 256 + lane * 4];
        uint2 p6 = *(const uint2*)&Yl[(size_t)s6 * 256 + lane * 4];
        uint2 p7 = *(const uint2*)&Yl[(size_t)s7 * 256 + lane * 4];
        acc.x += ((__uint_as_float(p0.x << 16) + __uint_as_float(p1.x << 16)) +
                  (__uint_as_float(p2.x << 16) + __uint_as_float(p3.x << 16))) +
                 ((__uint_as_float(p4.x << 16) + __uint_as_float(p5.x << 16)) +
                  (__uint_as_float(p6.x << 16) + __uint_as_float(p7.x << 16)));
        acc.y += ((__uint_as_float(p0.x & 0xFFFF0000u) + __uint_as_float(p1.x & 0xFFFF0000u)) +
                  (__uint_as_float(p2.x & 0xFFFF0000u) + __uint_as_float(p3.x & 0xFFFF0000u))) +
                 ((__uint_as_float(p4.x & 0xFFFF0000u) + __uint_as_float(p5.x & 0xFFFF0000u)) +
                  (__uint_as_float(p6.x & 0xFFFF0000u) + __uint_as_float(p7.x & 0xFFFF0000u)));
        acc.z += ((__uint_as_float(p0.y << 16) + __uint_as_float(p1.y << 16)) +
                  (__uint_as_float(p2.y << 16) + __uint_as_float(p3.y << 16))) +
                 ((__uint_as_float(p4.y << 16) + __uint_as_float(p5.y << 16)) +
                  (__uint_as_float(p6.y << 16) + __uint_as_float(p7.y << 16)));
        acc.w += ((__uint_as_float(p0.y & 0xFFFF0000u) + __uint_as_float(p1.y & 0xFFFF0000u)) +
                  (__uint_as_float(p2.y & 0xFFFF0000u) + __uint_as_float(p3.y & 0xFFFF0000u))) +
                 ((__uint_as_float(p4.y & 0xFFFF0000u) + __uint_as_float(p5.y & 0xFFFF0000u)) +
                  (__uint_as_float(p6.y & 0xFFFF0000u) + __uint_as_float(p7.y & 0xFFFF0000u)));
    }
    for (; e + 3 < e1; e += 4) {
        int s0 = ssrc[e], s1 = ssrc[e + 1], s2 = ssrc[e + 2], s3 = ssrc[e + 3];
        uint2 p = *(const uint2*)&Yl[(size_t)s0 * 256 + lane * 4];
        uint2 q = *(const uint2*)&Yl[(size_t)s1 * 256 + lane * 4];
        uint2 v = *(const uint2*)&Yl[(size_t)s2 * 256 + lane * 4];
        uint2 t = *(const uint2*)&Yl[(size_t)s3 * 256 + lane * 4];
        acc.x += (__uint_as_float(p.x << 16) + __uint_as_float(q.x << 16)) +
                 (__uint_as_float(v.x << 16) + __uint_as_float(t.x << 16));
        acc.y += (__uint_as_float(p.x & 0xFFFF0000u) + __uint_as_float(q.x & 0xFFFF0000u)) +
                 (__uint_as_float(v.x & 0xFFFF0000u) + __uint_as_float(t.x & 0xFFFF0000u));
        acc.z += (__uint_as_float(p.y << 16) + __uint_as_float(q.y << 16)) +
                 (__uint_as_float(v.y << 16) + __uint_as_float(t.y << 16));
        acc.w += (__uint_as_float(p.y & 0xFFFF0000u) + __uint_as_float(q.y & 0xFFFF0000u)) +
                 (__uint_as_float(v.y & 0xFFFF0000u) + __uint_as_float(t.y & 0xFFFF0000u));
    }
    for (; e < e1; ++e) {
        int s0 = ssrc[e];
        uint2 p = *(const uint2*)&Yl[(size_t)s0 * 256 + lane * 4];
        acc.x += __uint_as_float(p.x << 16);
        acc.y += __uint_as_float(p.x & 0xFFFF0000u);
        acc.z += __uint_as_float(p.y << 16);
        acc.w += __uint_as_float(p.y & 0xFFFF0000u);
    }
    float ic = invc[n];
    float4 b = *(const float4*)&bl0[lane * 4];
    float4 yr = *(const float4*)&Yr[(size_t)n * 256 + lane * 4];
    float hx = fmaxf(acc.x * ic + b.x + yr.x, 0.f);
    float hy = fmaxf(acc.y * ic + b.y + yr.y, 0.f);
    float hz = fmaxf(acc.z * ic + b.z + yr.z, 0.f);
    float hw = fmaxf(acc.w * ic + b.w + yr.w, 0.f);
    unsigned h0, h1, l0, l1;
    split2(hx, hy, &h0, &l0);
    split2(hz, hw, &h1, &l1);
    size_t offH = (size_t)n * 256 + lane * 4;   // node-major, fragment-k order: dense 512B/node
    *(uint2*)&Hh[offH] = make_uint2(h0, h1);
    *(uint2*)&Hl[offH] = make_uint2(l0, l1);
}

// ---------------- gemm1 v3: node-major A + fragment-ordered B (1 KB wave loads) ----------------

__global__ __launch_bounds__(256) void gemm1_mfma(const unsigned short* __restrict__ Hh,
                                                  const unsigned short* __restrict__ Hl,
                                                  const unsigned short* __restrict__ Bfh,
                                                  const unsigned short* __restrict__ Bfl,
                                                  unsigned short* __restrict__ Zl,
                                                  float* __restrict__ Zr, int N, int numTiles) {
    int tid = threadIdx.x;
    int lane = tid & 63;
    int w = __builtin_amdgcn_readfirstlane(tid >> 6);
    int ml = lane & 15, quad = lane >> 4;
    int t = blockIdx.x * 4 + w;
    if (t >= numTiles) return;

    const unsigned short* ahp = Hh + (size_t)(t * 16 + ml) * 256 + quad * 8;
    const unsigned short* alp = Hl + (size_t)(t * 16 + ml) * 256 + quad * 8;

    f32x4 acc[5];
    #pragma unroll
    for (int b = 0; b < 5; ++b) acc[b] = (f32x4){0.f, 0.f, 0.f, 0.f};

    #pragma unroll
    for (int kc = 0; kc < 8; ++kc) {
        bf16x8 ah = *(const bf16x8*)&ahp[kc * 32];
        bf16x8 al = *(const bf16x8*)&alp[kc * 32];
        #pragma unroll
        for (int nf = 0; nf < 5; ++nf) {
            size_t bo = (((size_t)(kc * 5 + nf)) * 64 + lane) * 8;
            bf16x8 bh = *(const bf16x8*)&Bfh[bo];
            bf16x8 bl = *(const bf16x8*)&Bfl[bo];
            acc[nf] = __builtin_amdgcn_mfma_f32_16x16x32_bf16(ah, bh, acc[nf], 0, 0, 0);
            acc[nf] = __builtin_amdgcn_mfma_f32_16x16x32_bf16(ah, bl, acc[nf], 0, 0, 0);
            acc[nf] = __builtin_amdgcn_mfma_f32_16x16x32_bf16(al, bh, acc[nf], 0, 0, 0);
        }
    }
    #pragma unroll
    for (int r = 0; r < 4; ++r) {
        int n = t * 16 + quad * 4 + r;
        if (n < N) {
            #pragma unroll
            for (int nf = 0; nf < 5; ++nf) {
                int col = nf * 16 + ml;
                if (col < 40) Zl[(size_t)n * 40 + col] = f2bf_rne(acc[nf][r]);
                else Zr[(size_t)n * 40 + (col - 40)] = acc[nf][r];
            }
        }
    }
}

// ---------------- combine1: bf16 Zl gather ----------------

__global__ __launch_bounds__(256) void combine1(const unsigned short* __restrict__ Zl,
                                                const float* __restrict__ Zr,
                                                const int* __restrict__ offs,
                                                const int* __restrict__ ssrc,
                                                const float* __restrict__ invc,
                                                const float* __restrict__ bl1,
                                                float* __restrict__ H2, int N) {
    int wv = threadIdx.x >> 6, lane = threadIdx.x & 63;
    int n = blockIdx.x * 4 + wv;
    if (n >= N) return;
    if (lane >= 40) return;
    int e0 = offs[n], e1 = offs[n + 1];
    float acc = 0.f;
    int e = e0;
    for (; e + 1 < e1; e += 2) {
        int s0 = ssrc[e], s1 = ssrc[e + 1];
        unsigned a = Zl[(size_t)s0 * 40 + lane];
        unsigned b = Zl[(size_t)s1 * 40 + lane];
        acc += __uint_as_float(a << 16) + __uint_as_float(b << 16);
    }
    if (e < e1) {
        unsigned a = Zl[(size_t)ssrc[e] * 40 + lane];
        acc += __uint_as_float(a << 16);
    }
    float v = acc * invc[n] + bl1[lane] + Zr[(size_t)n * 40 + lane];
    H2[(size_t)n * 40 + lane] = v;
}

// ---------------- W_lin pre-convert v2: fragment-ordered WbF ----------------
// WbF[slot][lane][8] bf16, slot = (c*3+s)*3+cf (c=0..19, s=0..2, cf=0..2), lane=0..63.

__global__ __launch_bounds__(256) void k_wprep(const float* __restrict__ W,
                                               unsigned short* __restrict__ WbF) {
    int idx = blockIdx.x * 256 + threadIdx.x;   // chunk index < 180*64
    if (idx >= 180 * 64) return;
    int slot = idx >> 6, lane = idx & 63;
    int cf = slot % 3;
    int cs = slot / 3;
    int s = cs % 3;
    int c = cs / 3;
    int ml = lane & 15, quad = lane >> 4;
    int col = cf * 16 + ml;
    int kbase = c * 96 + s * 32 + quad * 8;
    unsigned short v8[8];
    #pragma unroll
    for (int e = 0; e < 8; ++e) {
        int kp = kbase + e;
        int i = kp / 48;
        int j = kp - i * 48;
        float v = 0.f;
        if (col < 40 && i < 40 && j < 40) v = W[((size_t)(i * 40 + j)) * 40 + col];
        v8[e] = f2bf_rne(v);
    }
    *(uint4*)&WbF[(size_t)idx * 8] = *(uint4*)v8;
}

// ---------------- k_final_mfma v4: register windows + coalesced WbF + free VGPR budget ----

__global__ __launch_bounds__(256, 1) void k_final_mfma(const float* __restrict__ H2,
                                                       const unsigned short* __restrict__ WbF,
                                                       const float* __restrict__ blin,
                                                       float* __restrict__ out, int N) {
    int tid = threadIdx.x;
    int m0 = blockIdx.x * 64;
    int lane = tid & 63;
    int w = __builtin_amdgcn_readfirstlane(tid >> 6);
    int ml = lane & 15;
    int quad = lane >> 4;
    int row = w * 16 + ml;
    int gn = m0 + row;

    float g[48];
    float s2 = 0.f;
    #pragma unroll
    for (int q4 = 0; q4 < 10; ++q4) {
        float4 v = make_float4(0.f, 0.f, 0.f, 0.f);
        if (gn < N) v = *(const float4*)&H2[(size_t)gn * 40 + q4 * 4];
        g[q4 * 4 + 0] = v.x; g[q4 * 4 + 1] = v.y;
        g[q4 * 4 + 2] = v.z; g[q4 * 4 + 3] = v.w;
        s2 += v.x * v.x + v.y * v.y + v.z * v.z + v.w * v.w;
    }
    #pragma unroll
    for (int j = 40; j < 48; ++j) g[j] = 0.f;

    float aln = atanhf(fminf(fmaxf(s2, 1e-15f), 0.996f)) / fmaxf(s2, 1e-30f);

    bool isQ0 = (quad == 0), isQ2 = (quad == 2), qLo = (quad < 2);
    float wA[8], wB[8], wC[8];
    #pragma unroll
    for (int j = 0; j < 8; ++j) {
        float a0 = isQ0 ? g[j] : g[8 + j];
        float a1 = isQ2 ? g[16 + j] : g[24 + j];
        wA[j] = qLo ? a0 : a1;
        float b0 = isQ0 ? g[32 + j] : g[40 + j];
        float b1 = isQ2 ? g[j] : g[8 + j];
        wB[j] = qLo ? b0 : b1;
        float c0 = isQ0 ? g[16 + j] : g[24 + j];
        float c1 = isQ2 ? g[32 + j] : g[40 + j];
        wC[j] = qLo ? c0 : c1;
    }

    f32x4 acc[3];
    #pragma unroll
    for (int c = 0; c < 3; ++c) acc[c] = (f32x4){0.f, 0.f, 0.f, 0.f};

    const unsigned short* bw = WbF + (size_t)lane * 8;

    #pragma unroll
    for (int c = 0; c < 20; ++c) {
        float gi0 = g[2 * c];
        float gi1 = qLo ? g[2 * c] : g[2 * c + 1];
        float gi2 = g[2 * c + 1];
        {
            const int slot = (c * 3 + 0) * 3;
            union { unsigned u[4]; bf16x8 v; } A;
            A.u[0] = pack_bf16_hu(gi0 * wA[0], gi0 * wA[1]);
            A.u[1] = pack_bf16_hu(gi0 * wA[2], gi0 * wA[3]);
            A.u[2] = pack_bf16_hu(gi0 * wA[4], gi0 * wA[5]);
            A.u[3] = pack_bf16_hu(gi0 * wA[6], gi0 * wA[7]);
            #pragma unroll
            for (int cf = 0; cf < 3; ++cf) {
                bf16x8 bf = *(const bf16x8*)&bw[(size_t)(slot + cf) * 512];
                acc[cf] = __builtin_amdgcn_mfma_f32_16x16x32_bf16(A.v, bf, acc[cf], 0, 0, 0);
            }
        }
        {
            const int slot = (c * 3 + 1) * 3;
            union { unsigned u[4]; bf16x8 v; } A;
            A.u[0] = pack_bf16_hu(gi1 * wB[0], gi1 * wB[1]);
            A.u[1] = pack_bf16_hu(gi1 * wB[2], gi1 * wB[3]);
            A.u[2] = pack_bf16_hu(gi1 * wB[4], gi1 * wB[5]);
            A.u[3] = pack_bf16_hu(gi1 * wB[6], gi1 * wB[7]);
            #pragma unroll
            for (int cf = 0; cf < 3; ++cf) {
                bf16x8 bf = *(const bf16x8*)&bw[(size_t)(slot + cf) * 512];
                acc[cf] = __builtin_amdgcn_mfma_f32_16x16x32_bf16(A.v, bf, acc[cf], 0, 0, 0);
            }
        }
        {
            const int slot = (c * 3 + 2) * 3;
            union { unsigned u[4]; bf16x8 v; } A;
            A.u[0] = pack_bf16_hu(gi2 * wC[0], gi2 * wC[1]);
            A.u[1] = pack_bf16_hu(gi2 * wC[2], gi2 * wC[3]);
            A.u[2] = pack_bf16_hu(gi2 * wC[4], gi2 * wC[5]);
            A.u[3] = pack_bf16_hu(gi2 * wC[6], gi2 * wC[7]);
            #pragma unroll
            for (int cf = 0; cf < 3; ++cf) {
                bf16x8 bf = *(const bf16x8*)&bw[(size_t)(slot + cf) * 512];
                acc[cf] = __builtin_amdgcn_mfma_f32_16x16x32_bf16(A.v, bf, acc[cf], 0, 0, 0);
            }
        }
    }

    float bcol[3];
    #pragma unroll
    for (int c = 0; c < 3; ++c) {
        int col = c * 16 + ml;
        bcol[c] = (col < 40) ? blin[col] : 0.f;
    }
    bool v2 = (ml < 8);

    #pragma unroll
    for (int r = 0; r < 4; ++r) {
        int nloc = w * 16 + quad * 4 + r;
        float al = __shfl(aln, quad * 4 + r);
        float u0 = al * acc[0][r] + bcol[0];
        float u1 = al * acc[1][r] + bcol[1];
        float u2 = v2 ? (al * acc[2][r] + bcol[2]) : 0.f;
        float un2 = u0 * u0 + u1 * u1 + u2 * u2;
        #pragma unroll
        for (int m = 1; m < 16; m <<= 1) un2 += __shfl_xor(un2, m);
        float un = fmaxf(sqrtf(un2), 1e-15f);
        float tnh = tanhf(un);
        float gma = tnh / un;
        float ps = (tnh > 0.996f) ? (0.996f / tnh) : 1.0f;
        float s = gma * ps;
        float l0 = s * u0, l1 = s * u1, l2 = s * u2;
        float mx = fmaxf(l0, l1);
        if (v2) mx = fmaxf(mx, l2);
        #pragma unroll
        for (int m = 1; m < 16; m <<= 1) mx = fmaxf(mx, __shfl_xor(mx, m));
        float se = expf(l0 - mx) + expf(l1 - mx) + (v2 ? expf(l2 - mx) : 0.f);
        #pragma unroll
        for (int m = 1; m < 16; m <<= 1) se += __shfl_xor(se, m);
        float lse = logf(se);
        int go = m0 + nloc;
        if (go < N) {
            out[(size_t)go * 40 + ml] = l0 - mx - lse;
            out[(size_t)go * 40 + 16 + ml] = l1 - mx - lse;
            if (v2) out[(size_t)go * 40 + 32 + ml] = l2 - mx - lse;
        }
    }
}

// ---------------- launch ----------------

extern "C" void kernel_launch(void* const* d_in, const int* in_sizes, int n_in,
                              void* d_out, int out_size, void* d_ws, size_t ws_size,
                              hipStream_t stream) {
    const float* x    = (const float*)d_in[0];
    const int*   ei   = (const int*)d_in[1];
    const float* Wl0  = (const float*)d_in[2];
    const float* bl0  = (const float*)d_in[3];
    const float* Wr0  = (const float*)d_in[4];
    const float* Wl1  = (const float*)d_in[5];
    const float* bl1  = (const float*)d_in[6];
    const float* Wr1  = (const float*)d_in[7];
    const float* Wlin = (const float*)d_in[8];
    const float* blin = (const float*)d_in[9];
    int N = in_sizes[0] / 256;
    int E = in_sizes[1] / 2;
    const int* src = ei;
    const int* dst = ei + E;
    int numTiles = (N + 15) / 16;
    int Npad = ((N + 63) / 64) * 64;          // gemm0 tile-padded row count

    char* ws = (char*)d_ws;
    size_t off = 0;
    auto carve = [&](size_t bytes) -> char* {
        char* p = ws + off;
        off = (off + bytes + 255) & ~(size_t)255;
        return p;
    };
    size_t xbytes = (size_t)Npad * 256 * 2;   // >= numTiles*4096*2
    int*   deg    = (int*)carve((size_t)N * 4);
    int*   cursor = (int*)carve((size_t)N * 4);
    int*   offs   = (int*)carve((size_t)(N + 1) * 4);
    float* invc   = (float*)carve((size_t)N * 4);
    int*   bsum   = (int*)carve(1024);
    int*   ssrc   = (int*)carve((size_t)E * 4);
    unsigned short* Yl = (unsigned short*)carve((size_t)N * 256 * 2);
    float* Yr     = (float*)carve((size_t)N * 256 * 4);
    unsigned short* Hh = (unsigned short*)carve(xbytes);
    unsigned short* Hl = (unsigned short*)carve(xbytes);
    unsigned short* Zl = (unsigned short*)carve((size_t)N * 40 * 2);
    float* Zr     = (float*)carve((size_t)N * 40 * 4);
    float* H2     = (float*)carve((size_t)N * 40 * 4);
    // Xh/Xl (pre-split, swizzled X) alias Hh/Hl: dead before combine0 writes Hh/Hl
    unsigned short* Xh = Hh;
    unsigned short* Xl = Hl;
    // WbF (180*64*8 bf16 = 184 KB) aliases Yr (dead after combine0)
    unsigned short* Wb = (unsigned short*)Yr;
    // split weights alias H2 (written only at combine1, after gemm1)
    unsigned short* Wth  = (unsigned short*)H2;    // gemm0 fragment B: 256 KB
    unsigned short* Wtl  = Wth + 512 * 256;        // 256 KB
    unsigned short* Wt1h = Wtl + 512 * 256;        // gemm1 fragment B: 40 KB
    unsigned short* Wt1l = Wt1h + 80 * 256;

    int G = (N + 1023) / 1024;

    hipMemsetAsync(deg, 0, (size_t)N * 4, stream);
    hipMemsetAsync(cursor, 0, (size_t)N * 4, stream);

    k_count<<<(E + 255) / 256, 256, 0, stream>>>(dst, deg, E);
    k_scanA<<<G, 256, 0, stream>>>(deg, offs, invc, bsum, N);
    k_scanB<<<1, 64, 0, stream>>>(bsum, offs, N, G);
    k_scanC<<<G, 256, 0, stream>>>(offs, bsum, N);
    k_scatter<<<(E + 255) / 256, 256, 0, stream>>>(src, dst, offs, cursor, ssrc, E);
    k_wsplit0<<<64, 256, 0, stream>>>(Wl0, Wr0, Wth, Wtl);
    k_wsplit1<<<(40 * 64 + 255) / 256, 256, 0, stream>>>(Wl1, Wr1, Wt1h, Wt1l);
    k_xsplit<<<(Npad * 32) / 256, 256, 0, stream>>>(x, Xh, Xl, N);
    gemm0_mfma<<<(N + 63) / 64, 512, 0, stream>>>(Xh, Xl, Wth, Wtl, Yl, Yr, N);
    combine0<<<(N + 3) / 4, 256, 0, stream>>>(Yl, Yr, offs, ssrc, invc, bl0, Hh, Hl, N);
    k_wprep<<<(180 * 64 + 255) / 256, 256, 0, stream>>>(Wlin, Wb);   // after combine0 (Yr alias)
    gemm1_mfma<<<(numTiles + 3) / 4, 256, 0, stream>>>(Hh, Hl, Wt1h, Wt1l, Zl, Zr, N, numTiles);
    combine1<<<(N + 3) / 4, 256, 0, stream>>>(Zl, Zr, offs, ssrc, invc, bl1, H2, N);
    k_final_mfma<<<(N + 63) / 64, 256, 0, stream>>>(H2, Wb, blin, (float*)d_out, N);
}

// Round 15
// 396.275 us; speedup vs baseline: 1.1663x; 1.0650x over previous
//
#include <hip/hip_runtime.h>
#include <math.h>

// N=50000, F=256, H=256, C=40, E=800000; CURV=1, EPS=4e-3 -> maxnorm=0.996

typedef short bf16x8 __attribute__((ext_vector_type(8)));
typedef float f32x4 __attribute__((ext_vector_type(4)));

#define AS1 __attribute__((address_space(1)))
#define AS3 __attribute__((address_space(3)))

// pack two fp32 -> bf16x2 (round-half-up) : low short = a, high short = b
__device__ inline unsigned pack_bf16_hu(float a, float b) {
    unsigned ua = __float_as_uint(a) + 0x8000u;
    unsigned ub = __float_as_uint(b) + 0x8000u;
    return __builtin_amdgcn_perm(ub, ua, 0x07060302u);
}

__device__ inline unsigned short f2bf_rne(float x) {
    unsigned u = __float_as_uint(x);
    unsigned r = (u + 0x7fffu + ((u >> 16) & 1u)) >> 16;
    return (unsigned short)r;
}

// split (a,b) into hi bf16 pair + residual-lo bf16 pair (packed uints)
__device__ inline void split2(float a, float b, unsigned* hw, unsigned* lw) {
    unsigned ua = __float_as_uint(a) + 0x8000u;
    unsigned ub = __float_as_uint(b) + 0x8000u;
    *hw = __builtin_amdgcn_perm(ub, ua, 0x07060302u);
    float ra = a - __uint_as_float(ua & 0xFFFF0000u);
    float rb = b - __uint_as_float(ub & 0xFFFF0000u);
    unsigned va = __float_as_uint(ra) + 0x8000u;
    unsigned vb = __float_as_uint(rb) + 0x8000u;
    *lw = __builtin_amdgcn_perm(vb, va, 0x07060302u);
}

// ---------------- CSR build ----------------

__global__ void k_count(const int* __restrict__ dst, int* __restrict__ deg, int E) {
    int e = blockIdx.x * 256 + threadIdx.x;
    if (e < E) atomicAdd(&deg[dst[e]], 1);
}

__global__ __launch_bounds__(256) void k_scanA(const int* __restrict__ deg,
                                               int* __restrict__ offs,
                                               float* __restrict__ invc,
                                               int* __restrict__ bsum, int N) {
    __shared__ int wt[4];
    int tid = threadIdx.x, lane = tid & 63, wid = tid >> 6;
    int base = blockIdx.x * 1024 + tid * 4;
    int v[4];
    #pragma unroll
    for (int j = 0; j < 4; ++j) {
        int i = base + j;
        v[j] = (i < N) ? deg[i] : 0;
        if (i < N) invc[i] = 1.0f / (float)max(v[j], 1);
    }
    int t = v[0] + v[1] + v[2] + v[3];
    int s = t;
    #pragma unroll
    for (int d = 1; d < 64; d <<= 1) {
        int u = __shfl_up(s, d);
        if (lane >= d) s += u;
    }
    if (lane == 63) wt[wid] = s;
    __syncthreads();
    int wpre = 0, btot = 0;
    #pragma unroll
    for (int q = 0; q < 4; ++q) {
        int x = wt[q];
        btot += x;
        if (q < wid) wpre += x;
    }
    int run = wpre + s - t;
    #pragma unroll
    for (int j = 0; j < 4; ++j) {
        int i = base + j;
        if (i < N) offs[i] = run;
        run += v[j];
    }
    if (tid == 0) bsum[blockIdx.x] = btot;
}

// k_scanC v2: absorbs k_scanB. Each block wave-reduces its own exclusive prefix of
// bsum[0..bid) (G<=64 lanes loop-strided for generality); offs[N] = E (degree sum).

__global__ __launch_bounds__(256) void k_scanC(int* __restrict__ offs,
                                               const int* __restrict__ bsum,
                                               int N, int E, int G) {
    __shared__ int s_add;
    int tid = threadIdx.x;
    if (tid < 64) {
        int bid = blockIdx.x;
        int v = 0;
        for (int i = tid; i < G; i += 64)
            if (i < bid) v += bsum[i];
        #pragma unroll
        for (int d = 1; d < 64; d <<= 1) v += __shfl_xor(v, d);
        if (tid == 0) s_add = v;
    }
    __syncthreads();
    int add = s_add;
    int base = blockIdx.x * 1024 + tid * 4;
    #pragma unroll
    for (int j = 0; j < 4; ++j) {
        int i = base + j;
        if (i < N) offs[i] += add;
    }
    if (blockIdx.x == 0 && tid == 0) offs[N] = E;
}

__global__ void k_scatter(const int* __restrict__ src, const int* __restrict__ dst,
                          const int* __restrict__ offs, int* __restrict__ cursor,
                          int* __restrict__ ssrc, int E) {
    int e = blockIdx.x * 256 + threadIdx.x;
    if (e >= E) return;
    int d = dst[e];
    int pos = offs[d] + atomicAdd(&cursor[d], 1);
    ssrc[pos] = src[e];
}

// ---------------- weight prep ----------------
// k_wsplit0 v2: emits FRAGMENT-ORDERED Bf for gemm0.
// Bf[(w*8+g)*4+nf][lane][8] bf16: per-slot 64 lanes x 16B contiguous (1 KB wave load).

__global__ __launch_bounds__(256) void k_wsplit0(const float* __restrict__ Wl,
                                                 const float* __restrict__ Wr,
                                                 unsigned short* __restrict__ Bfh,
                                                 unsigned short* __restrict__ Bfl) {
    int idx = blockIdx.x * 256 + threadIdx.x;   // < 8*8*4*64 = 16384 lane-chunks
    int lane = idx & 63;
    int nf = (idx >> 6) & 3;
    int g  = (idx >> 8) & 7;
    int w  = (idx >> 11) & 7;
    int ml = lane & 15, quad = lane >> 4;
    int wc = w & 3;
    int n = (w < 4) ? (wc * 64 + (nf & 2) * 16 + 2 * ml + (nf & 1))
                    : (256 + wc * 64 + nf * 16 + ml);
    int kbase = g * 32 + quad * 8;
    unsigned short h8[8], l8[8];
    #pragma unroll
    for (int e = 0; e < 8; ++e) {
        int k = kbase + e;
        float v = (n < 256) ? Wl[k * 256 + n] : Wr[k * 256 + (n - 256)];
        unsigned short h = f2bf_rne(v);
        float hf = __uint_as_float(((unsigned)h) << 16);
        h8[e] = h;
        l8[e] = f2bf_rne(v - hf);
    }
    *(uint4*)&Bfh[(size_t)idx * 8] = *(uint4*)h8;
    *(uint4*)&Bfl[(size_t)idx * 8] = *(uint4*)l8;
}

// k_wsplit1 v2: FRAGMENT-ORDERED Bf1 for gemm1.
// Bf1[kc*5+nf][lane][8] bf16; n = nf*16+ml (<80), k = kc*32+quad*8+e.

__global__ __launch_bounds__(256) void k_wsplit1(const float* __restrict__ Wl,
                                                 const float* __restrict__ Wr,
                                                 unsigned short* __restrict__ Bfh,
                                                 unsigned short* __restrict__ Bfl) {
    int idx = blockIdx.x * 256 + threadIdx.x;   // < 40*64 = 2560 lane-chunks
    if (idx >= 40 * 64) return;
    int lane = idx & 63;
    int slot = idx >> 6;        // 0..39
    int nf = slot % 5;
    int kc = slot / 5;
    int ml = lane & 15, quad = lane >> 4;
    int n = nf * 16 + ml;
    int kbase = kc * 32 + quad * 8;
    unsigned short h8[8], l8[8];
    #pragma unroll
    for (int e = 0; e < 8; ++e) {
        int k = kbase + e;
        float v = (n < 40) ? Wl[k * 40 + n] : Wr[k * 40 + (n - 40)];
        unsigned short h = f2bf_rne(v);
        float hf = __uint_as_float(((unsigned)h) << 16);
        h8[e] = h;
        l8[e] = f2bf_rne(v - hf);
    }
    *(uint4*)&Bfh[(size_t)idx * 8] = *(uint4*)h8;
    *(uint4*)&Bfl[(size_t)idx * 8] = *(uint4*)l8;
}

// ---------------- X pre-split: X fp32 -> Xh/Xl bf16, chunk-XOR-swizzled rows ----------------

__global__ __launch_bounds__(256) void k_xsplit(const float* __restrict__ X,
                                                unsigned short* __restrict__ Xh,
                                                unsigned short* __restrict__ Xl,
                                                int N) {
    int idx = blockIdx.x * 256 + threadIdx.x;   // n*32 + c over Npad rows
    int n = idx >> 5, c = idx & 31;
    float4 v0 = make_float4(0.f, 0.f, 0.f, 0.f);
    float4 v1 = make_float4(0.f, 0.f, 0.f, 0.f);
    if (n < N) {
        v0 = *(const float4*)&X[(size_t)n * 256 + c * 8];
        v1 = *(const float4*)&X[(size_t)n * 256 + c * 8 + 4];
    }
    unsigned h0, l0, h1, l1, h2, l2, h3, l3;
    split2(v0.x, v0.y, &h0, &l0);
    split2(v0.z, v0.w, &h1, &l1);
    split2(v1.x, v1.y, &h2, &l2);
    split2(v1.z, v1.w, &h3, &l3);
    int cp = c ^ (n & 7);
    size_t o = (size_t)n * 256 + cp * 8;
    *(uint4*)&Xh[o] = make_uint4(h0, h1, h2, h3);
    *(uint4*)&Xl[o] = make_uint4(l0, l1, l2, l3);
}

// ---------------- gemm0 v6 (round-11 best): M=64, fragment dbuf B, 2-phase stage ----------------
// Occupancy experiments R6/R12/R13 all lost to this config. Do not re-litigate.

__global__ __launch_bounds__(512) void gemm0_mfma(const unsigned short* __restrict__ Xh,
                                                  const unsigned short* __restrict__ Xl,
                                                  const unsigned short* __restrict__ Bfh,
                                                  const unsigned short* __restrict__ Bfl,
                                                  unsigned short* __restrict__ Yl,
                                                  float* __restrict__ Yr, int N) {
    __shared__ __align__(16) unsigned short AhL[2][64 * 128];
    __shared__ __align__(16) unsigned short AlL[2][64 * 128];

    int tid = threadIdx.x;
    int lane = tid & 63;
    int w = __builtin_amdgcn_readfirstlane(tid >> 6);   // 0..7
    int ml = lane & 15, quad = lane >> 4;
    int m0 = blockIdx.x * 64;
    bool isYl = (w < 4);
    int wc = w & 3;

    auto stage = [&](int h) {
        #pragma unroll
        for (int j = 0; j < 2; ++j) {
            int idx = j * 512 + tid;            // 0..1023 16B-chunks
            int row = idx >> 4, c16 = idx & 15;
            size_t gsrc = (size_t)(m0 + row) * 512 + (size_t)h * 256 + c16 * 16;
            int loff = idx * 16;
            __builtin_amdgcn_global_load_lds((const AS1 unsigned*)((const char*)Xh + gsrc),
                                             (AS3 unsigned*)((char*)&AhL[h][0] + loff), 16, 0, 0);
            __builtin_amdgcn_global_load_lds((const AS1 unsigned*)((const char*)Xl + gsrc),
                                             (AS3 unsigned*)((char*)&AlL[h][0] + loff), 16, 0, 0);
        }
    };

    stage(0);

    f32x4 acc[4][4];
    #pragma unroll
    for (int a = 0; a < 4; ++a)
        #pragma unroll
        for (int b = 0; b < 4; ++b) acc[a][b] = (f32x4){0.f, 0.f, 0.f, 0.f};

    bf16x8 bh0[4], bl0[4], bh1[4], bl1[4];

    auto loadB = [&](int it, bf16x8* bh, bf16x8* bl) {
        size_t base = (((size_t)(w * 8 + it) * 4) * 64 + lane) * 8;
        #pragma unroll
        for (int nf = 0; nf < 4; ++nf) {
            bh[nf] = *(const bf16x8*)&Bfh[base + (size_t)nf * 512];
            bl[nf] = *(const bf16x8*)&Bfl[base + (size_t)nf * 512];
        }
    };

    loadB(0, bh0, bl0);
    __syncthreads();   // drains stage(0): half-0 ready

    int swz = ml & 7;

    #pragma unroll
    for (int p = 0; p < 2; ++p) {
        if (p == 0) stage(1);               // half-1 in flight across half-0 compute
        const char* base_h = (const char*)&AhL[p][0];
        const char* base_l = (const char*)&AlL[p][0];
        #pragma unroll
        for (int g2 = 0; g2 < 4; ++g2) {
            int g = p * 4 + g2;
            bf16x8* bhc = (g & 1) ? bh1 : bh0;
            bf16x8* blc = (g & 1) ? bl1 : bl0;
            bf16x8* bhn = (g & 1) ? bh0 : bh1;
            bf16x8* bln = (g & 1) ? bl0 : bl1;
            if (g < 7) loadB(g + 1, bhn, bln);
            bf16x8 ah[4], al[4];
            #pragma unroll
            for (int mf = 0; mf < 4; ++mf) {
                int ro = (mf * 16 + ml) * 256 + (((g2 * 4 + quad) ^ swz) * 16);
                ah[mf] = *(const bf16x8*)(base_h + ro);
                al[mf] = *(const bf16x8*)(base_l + ro);
            }
            #pragma unroll
            for (int nf = 0; nf < 4; ++nf)
                #pragma unroll
                for (int mf = 0; mf < 4; ++mf) {
                    acc[mf][nf] = __builtin_amdgcn_mfma_f32_16x16x32_bf16(ah[mf], bhc[nf], acc[mf][nf], 0, 0, 0);
                    acc[mf][nf] = __builtin_amdgcn_mfma_f32_16x16x32_bf16(ah[mf], blc[nf], acc[mf][nf], 0, 0, 0);
                    acc[mf][nf] = __builtin_amdgcn_mfma_f32_16x16x32_bf16(al[mf], bhc[nf], acc[mf][nf], 0, 0, 0);
                }
        }
        if (p == 0) __syncthreads();        // drains stage(1); all half-0 reads done
    }

    if (isYl) {
        #pragma unroll
        for (int mf = 0; mf < 4; ++mf)
            #pragma unroll
            for (int r = 0; r < 4; ++r) {
                int row = m0 + mf * 16 + quad * 4 + r;
                if (row < N) {
                    unsigned p0 = pack_bf16_hu(acc[mf][0][r], acc[mf][1][r]);
                    unsigned p1 = pack_bf16_hu(acc[mf][2][r], acc[mf][3][r]);
                    *(unsigned*)&Yl[(size_t)row * 256 + wc * 64 + 2 * ml] = p0;
                    *(unsigned*)&Yl[(size_t)row * 256 + wc * 64 + 32 + 2 * ml] = p1;
                }
            }
    } else {
        #pragma unroll
        for (int mf = 0; mf < 4; ++mf)
            #pragma unroll
            for (int r = 0; r < 4; ++r) {
                int row = m0 + mf * 16 + quad * 4 + r;
                if (row < N) {
                    #pragma unroll
                    for (int nf = 0; nf < 4; ++nf)
                        Yr[(size_t)row * 256 + wc * 64 + nf * 16 + ml] = acc[mf][nf][r];
                }
            }
    }
}

// ---------------- combine0 v3: 1 node/wave + 8-deep MLP + dense node-major H writes ----------------

__global__ __launch_bounds__(256) void combine0(const unsigned short* __restrict__ Yl,
                                                const float* __restrict__ Yr,
                                                const int* __restrict__ offs,
                                                const int* __restrict__ ssrc,
                                                const float* __restrict__ invc,
                                                const float* __restrict__ bl0,
                                                unsigned short* __restrict__ Hh,
                                                unsigned short* __restrict__ Hl, int N) {
    int wv = threadIdx.x >> 6, lane = threadIdx.x & 63;
    int n = blockIdx.x * 4 + wv;
    if (n >= N) return;
    int e0 = offs[n], e1 = offs[n + 1];
    float4 acc = make_float4(0.f, 0.f, 0.f, 0.f);
    int e = e0;
    for (; e + 7 < e1; e += 8) {
        int s0 = ssrc[e],     s1 = ssrc[e + 1], s2 = ssrc[e + 2], s3 = ssrc[e + 3];
        int s4 = ssrc[e + 4], s5 = ssrc[e + 5], s6 = ssrc[e + 6], s7 = ssrc[e + 7];
        uint2 p0 = *(const uint2*)&Yl[(size_t)s0 * 256 + lane * 4];
        uint2 p1 = *(const uint2*)&Yl[(size_t)s1 * 256 + lane * 4];
        uint2 p2 = *(const uint2*)&Yl[(size_t)s2 * 256 + lane * 4];
        uint2 p3 = *(const uint2*)&Yl[(size_t)s3 * 256 + lane * 4];
        uint2 p4 = *(const uint2*)&Yl[(size_t)s4 * 256 + lane * 4];
        uint2 p5 = *(const uint2*)&Yl[(size_t)s5 * 256 + lane * 4];
        uint2 p6 = *(const uint2*)&Yl[(size_t)s6 * 256 + lane * 4];
        uint2 p7 = *(const uint2*)&Yl[(size_t)s7 * 256 + lane * 4];
        acc.x += ((__uint_as_float(p0.x << 16) + __uint_as_float(p1.x << 16)) +
                  (__uint_as_float(p2.x << 16) + __uint_as_float(p3.x << 16))) +
                 ((__uint_as_float(p4.x << 16) + __uint_as_float(p5.x << 16)) +
                  (__uint_as_float(p6.x << 16) + __uint_as_float(p7.x << 16)));
        acc.y += ((__uint_as_float(p0.x & 0xFFFF0000u) + __uint_as_float(p1.x & 0xFFFF0000u)) +
                  (__uint_as_float(p2.x & 0xFFFF0000u) + __uint_as_float(p3.x & 0xFFFF0000u))) +
                 ((__uint_as_float(p4.x & 0xFFFF0000u) + __uint_as_float(p5.x & 0xFFFF0000u)) +
                  (__uint_as_float(p6.x & 0xFFFF0000u) + __uint_as_float(p7.x & 0xFFFF0000u)));
        acc.z += ((__uint_as_float(p0.y << 16) + __uint_as_float(p1.y << 16)) +
                  (__uint_as_float(p2.y << 16) + __uint_as_float(p3.y << 16))) +
                 ((__uint_as_float(p4.y << 16) + __uint_as_float(p5.y << 16)) +
                  (__uint_as_float(p6.y << 16) + __uint_as_float(p7.y << 16)));
        acc.w += ((__uint_as_float(p0.y & 0xFFFF0000u) + __uint_as_float(p1.y & 0xFFFF0000u)) +
                  (__uint_as_float(p2.y & 0xFFFF0000u) + __uint_as_float(p3.y & 0xFFFF0000u))) +
                 ((__uint_as_float(p4.y & 0xFFFF0000u) + __uint_as_float(p5.y & 0xFFFF0000u)) +
                  (__uint_as_float(p6.y & 0xFFFF0000u) + __uint_as_float(p7.y & 0xFFFF0000u)));
    }
    for (; e + 3 < e1; e += 4) {
        int s0 = ssrc[e], s1 = ssrc[e + 1], s2 = ssrc[e + 2], s3 = ssrc[e + 3];
        uint2 p = *(const uint2*)&Yl[(size_t)s0 * 256 + lane * 4];
        uint2 q = *(const uint2*)&Yl[(size_t)s1 * 256 + lane * 4];
        uint2 v = *(const uint2*)&Yl[(size_t)s2 * 256 + lane * 4];
        uint2 t = *(const uint2*)&Yl[(size_t)s3 * 256 + lane * 4];
        acc.x += (__uint_as_float(p.x << 16) + __uint_as_float(q.x << 16)) +
                 (__uint_as_float(v.x << 16) + __uint_as_float(t.x << 16));
        acc.y += (__uint_as_float(p.x & 0xFFFF0000u) + __uint_as_float(q.x & 0xFFFF0000u)) +
                 (__uint_as_float(v.x & 0xFFFF0000u) + __uint_as_float(t.x & 0xFFFF0000u));
        acc.z += (__uint_as_float(p.y << 16) + __uint_as_float(q.y << 16)) +
                 (__uint_as_float(v.y << 16) + __uint_as_float(t.y << 16));
        acc.w += (__uint_as_float(p.y & 0xFFFF0000u) + __uint_as_float(q.y & 0xFFFF0000u)) +
                 (__uint_as_float(v.y & 0xFFFF0000u) + __uint_as_float(t.y & 0xFFFF0000u));
    }
    for (; e < e1; ++e) {
        int s0 = ssrc[e];
        uint2 p = *(const uint2*)&Yl[(size_t)s0 * 256 + lane * 4];
        acc.x += __uint_as_float(p.x << 16);
        acc.y += __uint_as_float(p.x & 0xFFFF0000u);
        acc.z += __uint_as_float(p.y << 16);
        acc.w += __uint_as_float(p.y & 0xFFFF0000u);
    }
    float ic = invc[n];
    float4 b = *(const float4*)&bl0[lane * 4];
    float4 yr = *(const float4*)&Yr[(size_t)n * 256 + lane * 4];
    float hx = fmaxf(acc.x * ic + b.x + yr.x, 0.f);
    float hy = fmaxf(acc.y * ic + b.y + yr.y, 0.f);
    float hz = fmaxf(acc.z * ic + b.z + yr.z, 0.f);
    float hw = fmaxf(acc.w * ic + b.w + yr.w, 0.f);
    unsigned h0, h1, l0, l1;
    split2(hx, hy, &h0, &l0);
    split2(hz, hw, &h1, &l1);
    size_t offH = (size_t)n * 256 + lane * 4;   // node-major, fragment-k order: dense 512B/node
    *(uint2*)&Hh[offH] = make_uint2(h0, h1);
    *(uint2*)&Hl[offH] = make_uint2(l0, l1);
}

// ---------------- gemm1 v3: node-major A + fragment-ordered B (1 KB wave loads) ----------------

__global__ __launch_bounds__(256) void gemm1_mfma(const unsigned short* __restrict__ Hh,
                                                  const unsigned short* __restrict__ Hl,
                                                  const unsigned short* __restrict__ Bfh,
                                                  const unsigned short* __restrict__ Bfl,
                                                  unsigned short* __restrict__ Zl,
                                                  float* __restrict__ Zr, int N, int numTiles) {
    int tid = threadIdx.x;
    int lane = tid & 63;
    int w = __builtin_amdgcn_readfirstlane(tid >> 6);
    int ml = lane & 15, quad = lane >> 4;
    int t = blockIdx.x * 4 + w;
    if (t >= numTiles) return;

    const unsigned short* ahp = Hh + (size_t)(t * 16 + ml) * 256 + quad * 8;
    const unsigned short* alp = Hl + (size_t)(t * 16 + ml) * 256 + quad * 8;

    f32x4 acc[5];
    #pragma unroll
    for (int b = 0; b < 5; ++b) acc[b] = (f32x4){0.f, 0.f, 0.f, 0.f};

    #pragma unroll
    for (int kc = 0; kc < 8; ++kc) {
        bf16x8 ah = *(const bf16x8*)&ahp[kc * 32];
        bf16x8 al = *(const bf16x8*)&alp[kc * 32];
        #pragma unroll
        for (int nf = 0; nf < 5; ++nf) {
            size_t bo = (((size_t)(kc * 5 + nf)) * 64 + lane) * 8;
            bf16x8 bh = *(const bf16x8*)&Bfh[bo];
            bf16x8 bl = *(const bf16x8*)&Bfl[bo];
            acc[nf] = __builtin_amdgcn_mfma_f32_16x16x32_bf16(ah, bh, acc[nf], 0, 0, 0);
            acc[nf] = __builtin_amdgcn_mfma_f32_16x16x32_bf16(ah, bl, acc[nf], 0, 0, 0);
            acc[nf] = __builtin_amdgcn_mfma_f32_16x16x32_bf16(al, bh, acc[nf], 0, 0, 0);
        }
    }
    #pragma unroll
    for (int r = 0; r < 4; ++r) {
        int n = t * 16 + quad * 4 + r;
        if (n < N) {
            #pragma unroll
            for (int nf = 0; nf < 5; ++nf) {
                int col = nf * 16 + ml;
                if (col < 40) Zl[(size_t)n * 40 + col] = f2bf_rne(acc[nf][r]);
                else Zr[(size_t)n * 40 + (col - 40)] = acc[nf][r];
            }
        }
    }
}

// ---------------- combine1 v2: 8-deep gather MLP (Zl is L2-resident broadcast) ----------------

__global__ __launch_bounds__(256) void combine1(const unsigned short* __restrict__ Zl,
                                                const float* __restrict__ Zr,
                                                const int* __restrict__ offs,
                                                const int* __restrict__ ssrc,
                                                const float* __restrict__ invc,
                                                const float* __restrict__ bl1,
                                                float* __restrict__ H2, int N) {
    int wv = threadIdx.x >> 6, lane = threadIdx.x & 63;
    int n = blockIdx.x * 4 + wv;
    if (n >= N) return;
    if (lane >= 40) return;
    int e0 = offs[n], e1 = offs[n + 1];
    float acc = 0.f;
    int e = e0;
    for (; e + 7 < e1; e += 8) {
        int s0 = ssrc[e],     s1 = ssrc[e + 1], s2 = ssrc[e + 2], s3 = ssrc[e + 3];
        int s4 = ssrc[e + 4], s5 = ssrc[e + 5], s6 = ssrc[e + 6], s7 = ssrc[e + 7];
        unsigned a0 = Zl[(size_t)s0 * 40 + lane];
        unsigned a1 = Zl[(size_t)s1 * 40 + lane];
        unsigned a2 = Zl[(size_t)s2 * 40 + lane];
        unsigned a3 = Zl[(size_t)s3 * 40 + lane];
        unsigned a4 = Zl[(size_t)s4 * 40 + lane];
        unsigned a5 = Zl[(size_t)s5 * 40 + lane];
        unsigned a6 = Zl[(size_t)s6 * 40 + lane];
        unsigned a7 = Zl[(size_t)s7 * 40 + lane];
        acc += ((__uint_as_float(a0 << 16) + __uint_as_float(a1 << 16)) +
                (__uint_as_float(a2 << 16) + __uint_as_float(a3 << 16))) +
               ((__uint_as_float(a4 << 16) + __uint_as_float(a5 << 16)) +
                (__uint_as_float(a6 << 16) + __uint_as_float(a7 << 16)));
    }
    for (; e + 1 < e1; e += 2) {
        int s0 = ssrc[e], s1 = ssrc[e + 1];
        unsigned a = Zl[(size_t)s0 * 40 + lane];
        unsigned b = Zl[(size_t)s1 * 40 + lane];
        acc += __uint_as_float(a << 16) + __uint_as_float(b << 16);
    }
    if (e < e1) {
        unsigned a = Zl[(size_t)ssrc[e] * 40 + lane];
        acc += __uint_as_float(a << 16);
    }
    float v = acc * invc[n] + bl1[lane] + Zr[(size_t)n * 40 + lane];
    H2[(size_t)n * 40 + lane] = v;
}

// ---------------- W_lin pre-convert v2: fragment-ordered WbF ----------------
// WbF[slot][lane][8] bf16, slot = (c*3+s)*3+cf (c=0..19, s=0..2, cf=0..2), lane=0..63.

__global__ __launch_bounds__(256) void k_wprep(const float* __restrict__ W,
                                               unsigned short* __restrict__ WbF) {
    int idx = blockIdx.x * 256 + threadIdx.x;   // chunk index < 180*64
    if (idx >= 180 * 64) return;
    int slot = idx >> 6, lane = idx & 63;
    int cf = slot % 3;
    int cs = slot / 3;
    int s = cs % 3;
    int c = cs / 3;
    int ml = lane & 15, quad = lane >> 4;
    int col = cf * 16 + ml;
    int kbase = c * 96 + s * 32 + quad * 8;
    unsigned short v8[8];
    #pragma unroll
    for (int e = 0; e < 8; ++e) {
        int kp = kbase + e;
        int i = kp / 48;
        int j = kp - i * 48;
        float v = 0.f;
        if (col < 40 && i < 40 && j < 40) v = W[((size_t)(i * 40 + j)) * 40 + col];
        v8[e] = f2bf_rne(v);
    }
    *(uint4*)&WbF[(size_t)idx * 8] = *(uint4*)v8;
}

// ---------------- k_final_mfma v4: register windows + coalesced WbF + free VGPR budget ----

__global__ __launch_bounds__(256, 1) void k_final_mfma(const float* __restrict__ H2,
                                                       const unsigned short* __restrict__ WbF,
                                                       const float* __restrict__ blin,
                                                       float* __restrict__ out, int N) {
    int tid = threadIdx.x;
    int m0 = blockIdx.x * 64;
    int lane = tid & 63;
    int w = __builtin_amdgcn_readfirstlane(tid >> 6);
    int ml = lane & 15;
    int quad = lane >> 4;
    int row = w * 16 + ml;
    int gn = m0 + row;

    float g[48];
    float s2 = 0.f;
    #pragma unroll
    for (int q4 = 0; q4 < 10; ++q4) {
        float4 v = make_float4(0.f, 0.f, 0.f, 0.f);
        if (gn < N) v = *(const float4*)&H2[(size_t)gn * 40 + q4 * 4];
        g[q4 * 4 + 0] = v.x; g[q4 * 4 + 1] = v.y;
        g[q4 * 4 + 2] = v.z; g[q4 * 4 + 3] = v.w;
        s2 += v.x * v.x + v.y * v.y + v.z * v.z + v.w * v.w;
    }
    #pragma unroll
    for (int j = 40; j < 48; ++j) g[j] = 0.f;

    float aln = atanhf(fminf(fmaxf(s2, 1e-15f), 0.996f)) / fmaxf(s2, 1e-30f);

    bool isQ0 = (quad == 0), isQ2 = (quad == 2), qLo = (quad < 2);
    float wA[8], wB[8], wC[8];
    #pragma unroll
    for (int j = 0; j < 8; ++j) {
        float a0 = isQ0 ? g[j] : g[8 + j];
        float a1 = isQ2 ? g[16 + j] : g[24 + j];
        wA[j] = qLo ? a0 : a1;
        float b0 = isQ0 ? g[32 + j] : g[40 + j];
        float b1 = isQ2 ? g[j] : g[8 + j];
        wB[j] = qLo ? b0 : b1;
        float c0 = isQ0 ? g[16 + j] : g[24 + j];
        float c1 = isQ2 ? g[32 + j] : g[40 + j];
        wC[j] = qLo ? c0 : c1;
    }

    f32x4 acc[3];
    #pragma unroll
    for (int c = 0; c < 3; ++c) acc[c] = (f32x4){0.f, 0.f, 0.f, 0.f};

    const unsigned short* bw = WbF + (size_t)lane * 8;

    #pragma unroll
    for (int c = 0; c < 20; ++c) {
        float gi0 = g[2 * c];
        float gi1 = qLo ? g[2 * c] : g[2 * c + 1];
        float gi2 = g[2 * c + 1];
        {
            const int slot = (c * 3 + 0) * 3;
            union { unsigned u[4]; bf16x8 v; } A;
            A.u[0] = pack_bf16_hu(gi0 * wA[0], gi0 * wA[1]);
            A.u[1] = pack_bf16_hu(gi0 * wA[2], gi0 * wA[3]);
            A.u[2] = pack_bf16_hu(gi0 * wA[4], gi0 * wA[5]);
            A.u[3] = pack_bf16_hu(gi0 * wA[6], gi0 * wA[7]);
            #pragma unroll
            for (int cf = 0; cf < 3; ++cf) {
                bf16x8 bf = *(const bf16x8*)&bw[(size_t)(slot + cf) * 512];
                acc[cf] = __builtin_amdgcn_mfma_f32_16x16x32_bf16(A.v, bf, acc[cf], 0, 0, 0);
            }
        }
        {
            const int slot = (c * 3 + 1) * 3;
            union { unsigned u[4]; bf16x8 v; } A;
            A.u[0] = pack_bf16_hu(gi1 * wB[0], gi1 * wB[1]);
            A.u[1] = pack_bf16_hu(gi1 * wB[2], gi1 * wB[3]);
            A.u[2] = pack_bf16_hu(gi1 * wB[4], gi1 * wB[5]);
            A.u[3] = pack_bf16_hu(gi1 * wB[6], gi1 * wB[7]);
            #pragma unroll
            for (int cf = 0; cf < 3; ++cf) {
                bf16x8 bf = *(const bf16x8*)&bw[(size_t)(slot + cf) * 512];
                acc[cf] = __builtin_amdgcn_mfma_f32_16x16x32_bf16(A.v, bf, acc[cf], 0, 0, 0);
            }
        }
        {
            const int slot = (c * 3 + 2) * 3;
            union { unsigned u[4]; bf16x8 v; } A;
            A.u[0] = pack_bf16_hu(gi2 * wC[0], gi2 * wC[1]);
            A.u[1] = pack_bf16_hu(gi2 * wC[2], gi2 * wC[3]);
            A.u[2] = pack_bf16_hu(gi2 * wC[4], gi2 * wC[5]);
            A.u[3] = pack_bf16_hu(gi2 * wC[6], gi2 * wC[7]);
            #pragma unroll
            for (int cf = 0; cf < 3; ++cf) {
                bf16x8 bf = *(const bf16x8*)&bw[(size_t)(slot + cf) * 512];
                acc[cf] = __builtin_amdgcn_mfma_f32_16x16x32_bf16(A.v, bf, acc[cf], 0, 0, 0);
            }
        }
    }

    float bcol[3];
    #pragma unroll
    for (int c = 0; c < 3; ++c) {
        int col = c * 16 + ml;
        bcol[c] = (col < 40) ? blin[col] : 0.f;
    }
    bool v2 = (ml < 8);

    #pragma unroll
    for (int r = 0; r < 4; ++r) {
        int nloc = w * 16 + quad * 4 + r;
        float al = __shfl(aln, quad * 4 + r);
        float u0 = al * acc[0][r] + bcol[0];
        float u1 = al * acc[1][r] + bcol[1];
        float u2 = v2 ? (al * acc[2][r] + bcol[2]) : 0.f;
        float un2 = u0 * u0 + u1 * u1 + u2 * u2;
        #pragma unroll
        for (int m = 1; m < 16; m <<= 1) un2 += __shfl_xor(un2, m);
        float un = fmaxf(sqrtf(un2), 1e-15f);
        float tnh = tanhf(un);
        float gma = tnh / un;
        float ps = (tnh > 0.996f) ? (0.996f / tnh) : 1.0f;
        float s = gma * ps;
        float l0 = s * u0, l1 = s * u1, l2 = s * u2;
        float mx = fmaxf(l0, l1);
        if (v2) mx = fmaxf(mx, l2);
        #pragma unroll
        for (int m = 1; m < 16; m <<= 1) mx = fmaxf(mx, __shfl_xor(mx, m));
        float se = expf(l0 - mx) + expf(l1 - mx) + (v2 ? expf(l2 - mx) : 0.f);
        #pragma unroll
        for (int m = 1; m < 16; m <<= 1) se += __shfl_xor(se, m);
        float lse = logf(se);
        int go = m0 + nloc;
        if (go < N) {
            out[(size_t)go * 40 + ml] = l0 - mx - lse;
            out[(size_t)go * 40 + 16 + ml] = l1 - mx - lse;
            if (v2) out[(size_t)go * 40 + 32 + ml] = l2 - mx - lse;
        }
    }
}

// ---------------- launch ----------------

extern "C" void kernel_launch(void* const* d_in, const int* in_sizes, int n_in,
                              void* d_out, int out_size, void* d_ws, size_t ws_size,
                              hipStream_t stream) {
    const float* x    = (const float*)d_in[0];
    const int*   ei   = (const int*)d_in[1];
    const float* Wl0  = (const float*)d_in[2];
    const float* bl0  = (const float*)d_in[3];
    const float* Wr0  = (const float*)d_in[4];
    const float* Wl1  = (const float*)d_in[5];
    const float* bl1  = (const float*)d_in[6];
    const float* Wr1  = (const float*)d_in[7];
    const float* Wlin = (const float*)d_in[8];
    const float* blin = (const float*)d_in[9];
    int N = in_sizes[0] / 256;
    int E = in_sizes[1] / 2;
    const int* src = ei;
    const int* dst = ei + E;
    int numTiles = (N + 15) / 16;
    int Npad = ((N + 63) / 64) * 64;          // gemm0 tile-padded row count

    char* ws = (char*)d_ws;
    size_t off = 0;
    auto carve = [&](size_t bytes) -> char* {
        char* p = ws + off;
        off = (off + bytes + 255) & ~(size_t)255;
        return p;
    };
    size_t xbytes = (size_t)Npad * 256 * 2;   // >= numTiles*4096*2
    int*   deg    = (int*)carve((size_t)(2 * N) * 4);   // deg[N] + cursor[N] contiguous
    int*   cursor = deg + N;
    int*   offs   = (int*)carve((size_t)(N + 1) * 4);
    float* invc   = (float*)carve((size_t)N * 4);
    int*   bsum   = (int*)carve(1024);
    int*   ssrc   = (int*)carve((size_t)E * 4);
    unsigned short* Yl = (unsigned short*)carve((size_t)N * 256 * 2);
    float* Yr     = (float*)carve((size_t)N * 256 * 4);
    unsigned short* Hh = (unsigned short*)carve(xbytes);
    unsigned short* Hl = (unsigned short*)carve(xbytes);
    unsigned short* Zl = (unsigned short*)carve((size_t)N * 40 * 2);
    float* Zr     = (float*)carve((size_t)N * 40 * 4);
    float* H2     = (float*)carve((size_t)N * 40 * 4);
    // Xh/Xl (pre-split, swizzled X) alias Hh/Hl: dead before combine0 writes Hh/Hl
    unsigned short* Xh = Hh;
    unsigned short* Xl = Hl;
    // WbF (180*64*8 bf16 = 184 KB) aliases Yr (dead after combine0)
    unsigned short* Wb = (unsigned short*)Yr;
    // split weights alias H2 (written only at combine1, after gemm1)
    unsigned short* Wth  = (unsigned short*)H2;    // gemm0 fragment B: 256 KB
    unsigned short* Wtl  = Wth + 512 * 256;        // 256 KB
    unsigned short* Wt1h = Wtl + 512 * 256;        // gemm1 fragment B: 40 KB
    unsigned short* Wt1l = Wt1h + 80 * 256;

    int G = (N + 1023) / 1024;

    hipMemsetAsync(deg, 0, (size_t)(2 * N) * 4, stream);   // deg + cursor in one pass

    k_count<<<(E + 255) / 256, 256, 0, stream>>>(dst, deg, E);
    k_scanA<<<G, 256, 0, stream>>>(deg, offs, invc, bsum, N);
    k_scanC<<<G, 256, 0, stream>>>(offs, bsum, N, E, G);
    k_scatter<<<(E + 255) / 256, 256, 0, stream>>>(src, dst, offs, cursor, ssrc, E);
    k_wsplit0<<<64, 256, 0, stream>>>(Wl0, Wr0, Wth, Wtl);
    k_wsplit1<<<(40 * 64 + 255) / 256, 256, 0, stream>>>(Wl1, Wr1, Wt1h, Wt1l);
    k_xsplit<<<(Npad * 32) / 256, 256, 0, stream>>>(x, Xh, Xl, N);
    gemm0_mfma<<<(N + 63) / 64, 512, 0, stream>>>(Xh, Xl, Wth, Wtl, Yl, Yr, N);
    combine0<<<(N + 3) / 4, 256, 0, stream>>>(Yl, Yr, offs, ssrc, invc, bl0, Hh, Hl, N);
    k_wprep<<<(180 * 64 + 255) / 256, 256, 0, stream>>>(Wlin, Wb);   // after combine0 (Yr alias)
    gemm1_mfma<<<(numTiles + 3) / 4, 256, 0, stream>>>(Hh, Hl, Wt1h, Wt1l, Zl, Zr, N, numTiles);
    combine1<<<(N + 3) / 4, 256, 0, stream>>>(Zl, Zr, offs, ssrc, invc, bl1, H2, N);
    k_final_mfma<<<(N + 63) / 64, 256, 0, stream>>>(H2, Wb, blin, (float*)d_out, N);
}